// Round 10
// baseline (523.664 us; speedup 1.0000x reference)
//
#include <hip/hip_runtime.h>
#include <hip/hip_fp16.h>
#include <cmath>

static inline int cdiv(long a, int b){ return (int)((a + b - 1) / b); }

__device__ __forceinline__ float lrelu(float x){ return x > 0.f ? x : 0.2f * x; }
__device__ __forceinline__ float elu1(float x){ return x > 0.f ? x : expm1f(x); }
__device__ __forceinline__ float fexp(float x){ return __expf(x); }   // native v_exp path
__device__ __forceinline__ float sel4(float4 v, int h){
  float ab = (h & 1) ? v.y : v.x;
  float cd = (h & 1) ? v.w : v.z;
  return (h & 2) ? cd : ab;
}

// compiler-level fence: keep LDS writes (phase1) before LDS reads (phase2)
// within the same wave; HW DS pipe is in-order per wave.
#define WAVE_FENCE() do { asm volatile("" ::: "memory"); __builtin_amdgcn_sched_barrier(0); } while(0)

#define W_SHIFT 7                 // 128 nodes per bucket
#define BUCKET_N (1 << W_SHIFT)
#define NBMAX   1024              // >= number of buckets (782)
#define NCHUNKS 512               // fixed grid: 2 blocks/CU
#define MS_THREADS 1024

// record: {src, dst_local, esc01(fp16x2), esc23(fp16x2)} — staged AND final CSR

// ---------------- CSR build (atomic-free scheduling) ----------------

__global__ __launch_bounds__(MS_THREADS)
void hist_chunks_kernel(const int* __restrict__ ei, int E, int CH, int* __restrict__ hist2d){
  __shared__ int s_b[NBMAX];
  int t = threadIdx.x, chunk = blockIdx.x;
  for (int i = t; i < NBMAX; i += MS_THREADS) s_b[i] = 0;
  __syncthreads();
  int lo = chunk * CH, hi = min(lo + CH, E);
  for (int e = lo + t; e < hi; e += MS_THREADS)
    atomicAdd(&s_b[ei[E + e] >> W_SHIFT], 1);
  __syncthreads();
  int* row = hist2d + (size_t)chunk * NBMAX;
  for (int i = t; i < NBMAX; i += MS_THREADS) row[i] = s_b[i];
}

__global__ __launch_bounds__(NCHUNKS)
void col_scan_kernel(int* __restrict__ hist2d, int* __restrict__ bcnt){
  __shared__ int s[NCHUNKS];
  int b = blockIdx.x, t = threadIdx.x;
  int v = hist2d[(size_t)t * NBMAX + b];
  s[t] = v; __syncthreads();
  #pragma unroll
  for (int off = 1; off < NCHUNKS; off <<= 1){
    int u = (t >= off) ? s[t - off] : 0;
    __syncthreads();
    s[t] += u;
    __syncthreads();
  }
  hist2d[(size_t)t * NBMAX + b] = s[t] - v;
  if (t == NCHUNKS - 1) bcnt[b] = s[t];
}

__global__ void scan_buckets_kernel(const int* __restrict__ bcnt, int nb, int total,
                                    int* __restrict__ bstart, int* __restrict__ row_start, int n){
  __shared__ int s[1024];
  int t = threadIdx.x;
  int v = (t < nb) ? bcnt[t] : 0;
  s[t] = v; __syncthreads();
  #pragma unroll
  for (int off = 1; off < 1024; off <<= 1){
    int u = (t >= off) ? s[t - off] : 0;
    __syncthreads();
    s[t] += u;
    __syncthreads();
  }
  bstart[t] = (t < nb) ? s[t] - v : total;
  if (t == 0){ bstart[NBMAX] = total; row_start[n] = total; }
}

// wev[d*4+h] = sum_c We1[d, h*8+c] * a_e1[h,c]
__global__ void wevec_kernel(const float* __restrict__ We, const float* __restrict__ ae,
                             float* __restrict__ wev){
  int i = threadIdx.x;
  if (i >= 32) return;
  int d = i >> 2, h = i & 3;
  float acc = 0.f;
  #pragma unroll
  for (int c = 0; c < 8; ++c) acc = fmaf(We[d * 32 + h * 8 + c], ae[h * 8 + c], acc);
  wev[d * 4 + h] = acc;
}

// multisplit: deterministic bases, no global atomics; stages one 16B record.
__global__ __launch_bounds__(MS_THREADS)
void multisplit_kernel(const int* __restrict__ ei, int E, int CH,
                       const float* __restrict__ eattr, const float* __restrict__ wev,
                       const int* __restrict__ bstart, const int* __restrict__ prefix2d,
                       int4* __restrict__ staged){
  __shared__ int s_hist[NBMAX];
  __shared__ int s_base[NBMAX];
  __shared__ float s_wev[32];
  int t = threadIdx.x, chunk = blockIdx.x;
  if (t < 32) s_wev[t] = wev[t];
  const int* pre = prefix2d + (size_t)chunk * NBMAX;
  for (int i = t; i < NBMAX; i += MS_THREADS){
    s_base[i] = bstart[i] + pre[i];
    s_hist[i] = 0;
  }
  __syncthreads();
  int lo = chunk * CH, hi = min(lo + CH, E);
  for (int e = lo + t; e < hi; e += MS_THREADS){
    int d = ei[E + e];
    int b = d >> W_SHIFT;
    const float4* ea = (const float4*)(eattr + (size_t)e * 8);
    float4 v0 = ea[0], v1 = ea[1];
    float av[8] = {v0.x, v0.y, v0.z, v0.w, v1.x, v1.y, v1.z, v1.w};
    float e0 = 0, e1 = 0, e2 = 0, e3 = 0;
    #pragma unroll
    for (int k = 0; k < 8; ++k){
      e0 = fmaf(av[k], s_wev[k * 4 + 0], e0);
      e1 = fmaf(av[k], s_wev[k * 4 + 1], e1);
      e2 = fmaf(av[k], s_wev[k * 4 + 2], e2);
      e3 = fmaf(av[k], s_wev[k * 4 + 3], e3);
    }
    __half2 h01 = __floats2half2_rn(e0, e1);
    __half2 h23 = __floats2half2_rn(e2, e3);
    int pos = s_base[b] + atomicAdd(&s_hist[b], 1);
    staged[pos] = make_int4(ei[e], d & (BUCKET_N - 1),
                            __builtin_bit_cast(int, h01), __builtin_bit_cast(int, h23));
  }
}

// per-bucket: count + per-node esc sums (LDS f32 atomics) -> row_start, selfesc;
// then permute staged records to final CSR order (one 16B store per edge).
__global__ __launch_bounds__(MS_THREADS)
void bucket_scatter_kernel(const int* __restrict__ bstart, const int4* __restrict__ staged,
                           int n, int* __restrict__ row_start, int4* __restrict__ recs,
                           float4* __restrict__ selfesc){
  __shared__ int s_cnt[BUCKET_N];
  __shared__ int s_cur[BUCKET_N];
  __shared__ float s_esc[BUCKET_N][4];
  int b = blockIdx.x, t = threadIdx.x;
  int node0 = b << W_SHIFT;
  if (t < BUCKET_N){
    s_cnt[t] = 0;
    s_esc[t][0] = 0.f; s_esc[t][1] = 0.f; s_esc[t][2] = 0.f; s_esc[t][3] = 0.f;
  }
  __syncthreads();
  int lo = bstart[b], hi = bstart[b + 1];
  for (int i = lo + t; i < hi; i += MS_THREADS){
    int4 r = staged[i];
    atomicAdd(&s_cnt[r.y], 1);
    float2 f01 = __half22float2(__builtin_bit_cast(__half2, r.z));
    float2 f23 = __half22float2(__builtin_bit_cast(__half2, r.w));
    atomicAdd(&s_esc[r.y][0], f01.x); atomicAdd(&s_esc[r.y][1], f01.y);
    atomicAdd(&s_esc[r.y][2], f23.x); atomicAdd(&s_esc[r.y][3], f23.y);
  }
  __syncthreads();
  if (t < BUCKET_N) s_cur[t] = s_cnt[t];
  __syncthreads();
  #pragma unroll
  for (int off = 1; off < BUCKET_N; off <<= 1){
    int v = (t < BUCKET_N && t >= off) ? s_cur[t - off] : 0;
    __syncthreads();
    if (t < BUCKET_N) s_cur[t] += v;
    __syncthreads();
  }
  if (t < BUCKET_N){
    int excl = s_cur[t] - s_cnt[t];
    int nd = node0 + t;
    if (nd <= n) row_start[nd] = lo + excl;
    if (nd < n){
      float inv = 1.f / fmaxf((float)s_cnt[t], 1.f);
      selfesc[nd] = make_float4(s_esc[t][0] * inv, s_esc[t][1] * inv,
                                s_esc[t][2] * inv, s_esc[t][3] * inv);
    }
    s_cur[t] = lo + excl;
  }
  __syncthreads();
  for (int i = lo + t; i < hi; i += MS_THREADS){
    int4 r = staged[i];
    int pos = atomicAdd(&s_cur[r.y], 1);
    recs[pos] = r;
  }
}

// ---------------- fused node transform + attention pre-scores ----------------
template<int K, int M, int C>
__global__ void gemm_score_kernel(const float* __restrict__ A, const float* __restrict__ W,
                                  const float* __restrict__ asrc, const float* __restrict__ adst,
                                  float* __restrict__ out, float* __restrict__ sS,
                                  float* __restrict__ sD, int n){
  __shared__ float Ws[K * M];
  __shared__ float s_as[M], s_ad[M];
  for (int i = threadIdx.x; i < K * M; i += blockDim.x) Ws[i] = W[i];
  if (threadIdx.x < M){ s_as[threadIdx.x] = asrc[threadIdx.x]; s_ad[threadIdx.x] = adst[threadIdx.x]; }
  __syncthreads();
  constexpr int ROWS = 256 / M;
  int row = blockIdx.x * ROWS + (int)threadIdx.x / M;
  int col = (int)threadIdx.x % M;
  if (row >= n) return;
  const float4* a4 = (const float4*)(A + (size_t)row * K);
  float acc = 0.f;
  #pragma unroll
  for (int k4 = 0; k4 < K / 4; ++k4){
    float4 av = a4[k4];
    acc = fmaf(av.x, Ws[(k4 * 4 + 0) * M + col], acc);
    acc = fmaf(av.y, Ws[(k4 * 4 + 1) * M + col], acc);
    acc = fmaf(av.z, Ws[(k4 * 4 + 2) * M + col], acc);
    acc = fmaf(av.w, Ws[(k4 * 4 + 3) * M + col], acc);
  }
  out[(size_t)row * M + col] = acc;
  float ps = acc * s_as[col], pd = acc * s_ad[col];
  #pragma unroll
  for (int off = 1; off < C; off <<= 1){
    ps += __shfl_xor(ps, off, 64);
    pd += __shfl_xor(pd, off, 64);
  }
  if ((col & (C - 1)) == 0){
    int h = col / C;
    sS[(size_t)row * 4 + h] = ps;
    sD[(size_t)row * 4 + h] = pd;
  }
}

// ---------------- CSR gather-aggregate ----------------
// MODE 0: concat heads + bias + ELU (layer1, OUT=32), EDGE: esc fp16x4 + selfesc
// MODE 1: mean heads + bias + ELU   (layer2, OUT=32)
// MODE 2: mean heads + bias         (layer3, OUT=4) — lane-per-edge path
template<int MODE, bool EDGE>
__global__ void gather_kernel(const int* __restrict__ row_start, const int4* __restrict__ recs,
                              const float4* __restrict__ selfesc,
                              const float* __restrict__ sS, const float* __restrict__ sD,
                              const float* __restrict__ xh, const float* __restrict__ bias,
                              float* __restrict__ out, int n){
  int wv = threadIdx.x >> 6, lane = threadIdx.x & 63;
  int node = blockIdx.x * 4 + wv;

  if constexpr (MODE == 2){
    if (node >= n) return;
    int rs = row_start[node], deg = row_start[node + 1] - rs;
    float4 sd4 = ((const float4*)sD)[node];
    float4 acc = {0,0,0,0}, dsum = {0,0,0,0};
    for (int k = lane; k < deg; k += 64){
      int s = recs[rs + k].x;
      float4 ss = ((const float4*)sS)[s];
      float4 w;
      w.x = fexp(lrelu(ss.x + sd4.x)); w.y = fexp(lrelu(ss.y + sd4.y));
      w.z = fexp(lrelu(ss.z + sd4.z)); w.w = fexp(lrelu(ss.w + sd4.w));
      dsum.x += w.x; dsum.y += w.y; dsum.z += w.z; dsum.w += w.w;
      float4 xv = ((const float4*)xh)[s];
      acc.x = fmaf(w.x, xv.x, acc.x); acc.y = fmaf(w.y, xv.y, acc.y);
      acc.z = fmaf(w.z, xv.z, acc.z); acc.w = fmaf(w.w, xv.w, acc.w);
    }
    #pragma unroll
    for (int off = 1; off < 64; off <<= 1){
      acc.x += __shfl_xor(acc.x, off, 64); acc.y += __shfl_xor(acc.y, off, 64);
      acc.z += __shfl_xor(acc.z, off, 64); acc.w += __shfl_xor(acc.w, off, 64);
      dsum.x += __shfl_xor(dsum.x, off, 64); dsum.y += __shfl_xor(dsum.y, off, 64);
      dsum.z += __shfl_xor(dsum.z, off, 64); dsum.w += __shfl_xor(dsum.w, off, 64);
    }
    if (lane == 0){
      float4 ssn = ((const float4*)sS)[node];
      float4 wsf;
      wsf.x = fexp(lrelu(ssn.x + sd4.x)); wsf.y = fexp(lrelu(ssn.y + sd4.y));
      wsf.z = fexp(lrelu(ssn.z + sd4.z)); wsf.w = fexp(lrelu(ssn.w + sd4.w));
      float4 xvn = ((const float4*)xh)[node];
      float v = (acc.x + wsf.x * xvn.x) / (dsum.x + wsf.x + 1e-16f)
              + (acc.y + wsf.y * xvn.y) / (dsum.y + wsf.y + 1e-16f)
              + (acc.z + wsf.z * xvn.z) / (dsum.z + wsf.z + 1e-16f)
              + (acc.w + wsf.w * xvn.w) / (dsum.w + wsf.w + 1e-16f);
      out[node] = 0.25f * v + bias[0];
    }
    return;
  } else {
  __shared__ float4 s_w[4][64];
  __shared__ int    s_src[4][64];
  if (node >= n) return;
  int rs = row_start[node], deg = row_start[node + 1] - rs;
  float4 sd4 = ((const float4*)sD)[node];
  int q = lane & 7;          // float4 column of the 32-wide row
  int h = q >> 1;            // head for this column group
  int sg = lane >> 3;        // slot group (8 edges per phase-2 slot set)
  float4 acc = {0,0,0,0};
  float dacc = 0.f;          // this lane's head denominator (partial)

  for (int base = 0; base < deg; base += 64){
    int k = base + lane;
    float4 w = {0,0,0,0}; int s = 0;
    if (k < deg){
      int4 rec = recs[rs + k];
      s = rec.x;
      float4 ss = ((const float4*)sS)[s];
      float a0 = ss.x + sd4.x, a1 = ss.y + sd4.y, a2 = ss.z + sd4.z, a3 = ss.w + sd4.w;
      if constexpr (EDGE){
        float2 f01 = __half22float2(__builtin_bit_cast(__half2, rec.z));
        float2 f23 = __half22float2(__builtin_bit_cast(__half2, rec.w));
        a0 += f01.x; a1 += f01.y; a2 += f23.x; a3 += f23.y;
      }
      w.x = fexp(lrelu(a0)); w.y = fexp(lrelu(a1));
      w.z = fexp(lrelu(a2)); w.w = fexp(lrelu(a3));
    }
    s_w[wv][lane] = w;
    s_src[wv][lane] = s;
    WAVE_FENCE();
    int nvalid = min(deg - base, 64);
    const float* s_wf = (const float*)&s_w[wv][0];
    #pragma unroll
    for (int i = 0; i < 8; ++i){
      int slot = i * 8 + sg;
      if (slot < nvalid){
        int s2 = s_src[wv][slot];
        float wg = s_wf[slot * 4 + h];
        float4 xv = ((const float4*)xh)[(size_t)s2 * 8 + q];
        dacc += wg;
        acc.x = fmaf(wg, xv.x, acc.x); acc.y = fmaf(wg, xv.y, acc.y);
        acc.z = fmaf(wg, xv.z, acc.z); acc.w = fmaf(wg, xv.w, acc.w);
      }
    }
    WAVE_FENCE();
  }

  // combine the 8 slot-group partials (acc + denominator together)
  #pragma unroll
  for (int off = 8; off < 64; off <<= 1){
    acc.x += __shfl_xor(acc.x, off, 64); acc.y += __shfl_xor(acc.y, off, 64);
    acc.z += __shfl_xor(acc.z, off, 64); acc.w += __shfl_xor(acc.w, off, 64);
    dacc  += __shfl_xor(dacc,  off, 64);
  }
  // self-loop: alpha = sS[node]+sD[node] (+ precomputed mean esc for layer 1)
  float4 ssn = ((const float4*)sS)[node];
  float a_self = sel4(ssn, h) + sel4(sd4, h);
  if constexpr (EDGE) a_self += sel4(selfesc[node], h);
  float wsel = fexp(lrelu(a_self));
  float4 xvn = ((const float4*)xh)[(size_t)node * 8 + q];
  acc.x = fmaf(wsel, xvn.x, acc.x); acc.y = fmaf(wsel, xvn.y, acc.y);
  acc.z = fmaf(wsel, xvn.z, acc.z); acc.w = fmaf(wsel, xvn.w, acc.w);
  dacc += wsel;
  float rin = 1.f / (dacc + 1e-16f);
  float4 val = {acc.x * rin, acc.y * rin, acc.z * rin, acc.w * rin};

  if constexpr (MODE == 0){
    float4 b4 = ((const float4*)bias)[q];
    val.x = elu1(val.x + b4.x); val.y = elu1(val.y + b4.y);
    val.z = elu1(val.z + b4.z); val.w = elu1(val.w + b4.w);
    if (lane < 8) ((float4*)out)[(size_t)node * 8 + lane] = val;
  } else {
    val.x += __shfl_xor(val.x, 2, 64); val.y += __shfl_xor(val.y, 2, 64);
    val.z += __shfl_xor(val.z, 2, 64); val.w += __shfl_xor(val.w, 2, 64);
    val.x += __shfl_xor(val.x, 4, 64); val.y += __shfl_xor(val.y, 4, 64);
    val.z += __shfl_xor(val.z, 4, 64); val.w += __shfl_xor(val.w, 4, 64);
    float4 b4 = ((const float4*)bias)[q & 1];
    val.x = elu1(val.x * 0.25f + b4.x); val.y = elu1(val.y * 0.25f + b4.y);
    val.z = elu1(val.z * 0.25f + b4.z); val.w = elu1(val.w * 0.25f + b4.w);
    if (lane < 2) ((float4*)out)[(size_t)node * 2 + lane] = val;
  }
  }
}

// ---------------- launcher ----------------

extern "C" void kernel_launch(void* const* d_in, const int* in_sizes, int n_in,
                              void* d_out, int out_size, void* d_ws, size_t ws_size,
                              hipStream_t stream){
  const float* x     = (const float*)d_in[0];
  const float* eattr = (const float*)d_in[1];
  const int*   ei    = (const int*)d_in[2];
  const float* W1  = (const float*)d_in[3];
  const float* as1 = (const float*)d_in[4];
  const float* ad1 = (const float*)d_in[5];
  const float* We1 = (const float*)d_in[6];
  const float* ae1 = (const float*)d_in[7];
  const float* b1  = (const float*)d_in[8];
  const float* W2  = (const float*)d_in[9];
  const float* as2 = (const float*)d_in[10];
  const float* ad2 = (const float*)d_in[11];
  const float* b2  = (const float*)d_in[12];
  const float* W3  = (const float*)d_in[13];
  const float* as3 = (const float*)d_in[14];
  const float* ad3 = (const float*)d_in[15];
  const float* b3  = (const float*)d_in[16];

  const int N = in_sizes[0] / 128;
  const int E = in_sizes[2] / 2;
  const int nb_buckets = (N + BUCKET_N - 1) >> W_SHIFT;   // 782 for N=100000
  const int CH = cdiv(E, NCHUNKS);

  // layout: [staged int4 E | recs int4 E | hist2d | selfesc | ints | wev]
  // floats (xh,sS,sD,h1,h2 = N*320 B = 32 MB) alias the staged region
  // (E*16 = 51.2 MB); staged is dead before the first gemm writes xh.
  char* b0 = (char*)d_ws;
  int4* staged = (int4*)b0;
  float* fp = (float*)b0;
  float* xh = fp; fp += (size_t)N * 32;
  float* sS = fp; fp += (size_t)N * 4;
  float* sD = fp; fp += (size_t)N * 4;
  float* h1 = fp; fp += (size_t)N * 32;
  float* h2 = fp; fp += (size_t)N * 8;
  int4* recs = (int4*)(b0 + (size_t)E * 16);
  int* hist2d = (int*)(b0 + (size_t)E * 32);
  float4* selfesc = (float4*)(hist2d + (size_t)NCHUNKS * NBMAX);
  int* ip = (int*)(selfesc + N);
  int* bcnt      = ip; ip += NBMAX;
  int* bstart    = ip; ip += NBMAX + 1;
  int* row_start = ip; ip += N + 1;
  float* wev = (float*)ip;

  const int B = 256;

  // ---- CSR build: plan (no global atomics) -> multisplit -> bucket scatter ----
  wevec_kernel<<<1, 32, 0, stream>>>(We1, ae1, wev);
  hist_chunks_kernel<<<NCHUNKS, MS_THREADS, 0, stream>>>(ei, E, CH, hist2d);
  col_scan_kernel<<<nb_buckets, NCHUNKS, 0, stream>>>(hist2d, bcnt);
  scan_buckets_kernel<<<1, 1024, 0, stream>>>(bcnt, nb_buckets, E, bstart, row_start, N);
  multisplit_kernel<<<NCHUNKS, MS_THREADS, 0, stream>>>(ei, E, CH, eattr, wev, bstart, hist2d, staged);
  bucket_scatter_kernel<<<nb_buckets, MS_THREADS, 0, stream>>>(bstart, staged, N, row_start, recs, selfesc);

  // ---- layer 1: 128 -> 4x8, concat, edge scores ----
  gemm_score_kernel<128,32,8><<<cdiv(N, 8), B, 0, stream>>>(x, W1, as1, ad1, xh, sS, sD, N);
  gather_kernel<0,true><<<cdiv(N, 4), B, 0, stream>>>(row_start, recs, selfesc, sS, sD, xh, b1, h1, N);

  // ---- layer 2: 32 -> 4x8, mean heads ----
  gemm_score_kernel<32,32,8><<<cdiv(N, 8), B, 0, stream>>>(h1, W2, as2, ad2, xh, sS, sD, N);
  gather_kernel<1,false><<<cdiv(N, 4), B, 0, stream>>>(row_start, recs, selfesc, sS, sD, xh, b2, h2, N);

  // ---- layer 3: 8 -> 4x1, mean heads ----
  gemm_score_kernel<8,4,1><<<cdiv(N, 64), B, 0, stream>>>(h2, W3, as3, ad3, xh, sS, sD, N);
  gather_kernel<2,false><<<cdiv(N, 4), B, 0, stream>>>(row_start, recs, selfesc, sS, sD, xh, b3, (float*)d_out, N);
}

// Round 11
// 464.561 us; speedup vs baseline: 1.1272x; 1.1272x over previous
//
#include <hip/hip_runtime.h>
#include <hip/hip_fp16.h>
#include <cmath>

static inline int cdiv(long a, int b){ return (int)((a + b - 1) / b); }

__device__ __forceinline__ float lrelu(float x){ return x > 0.f ? x : 0.2f * x; }
__device__ __forceinline__ float elu1(float x){ return x > 0.f ? x : expm1f(x); }
__device__ __forceinline__ float fexp(float x){ return __expf(x); }   // native v_exp path
__device__ __forceinline__ float sel4(float4 v, int h){
  float ab = (h & 1) ? v.y : v.x;
  float cd = (h & 1) ? v.w : v.z;
  return (h & 2) ? cd : ab;
}

// compiler-level fence: keep LDS writes (phase1) before LDS reads (phase2)
// within the same wave; HW DS pipe is in-order per wave.
#define WAVE_FENCE() do { asm volatile("" ::: "memory"); __builtin_amdgcn_sched_barrier(0); } while(0)

#define W_SHIFT 7                 // 128 nodes per bucket
#define BUCKET_N (1 << W_SHIFT)
#define NBMAX   1024              // >= number of buckets (782)
#define NCHUNKS 512               // fixed grid: 2 blocks/CU
#define MS_THREADS 1024

// record: {src, dst_local, esc01(fp16x2), esc23(fp16x2)} — staged AND final CSR

// ---------------- CSR build (atomic-free scheduling) ----------------

__global__ __launch_bounds__(MS_THREADS)
void hist_chunks_kernel(const int* __restrict__ ei, int E, int CH, int* __restrict__ hist2d){
  __shared__ int s_b[NBMAX];
  int t = threadIdx.x, chunk = blockIdx.x;
  for (int i = t; i < NBMAX; i += MS_THREADS) s_b[i] = 0;
  __syncthreads();
  int lo = chunk * CH, hi = min(lo + CH, E);
  for (int e = lo + t; e < hi; e += MS_THREADS)
    atomicAdd(&s_b[ei[E + e] >> W_SHIFT], 1);
  __syncthreads();
  int* row = hist2d + (size_t)chunk * NBMAX;
  for (int i = t; i < NBMAX; i += MS_THREADS) row[i] = s_b[i];
}

__global__ __launch_bounds__(NCHUNKS)
void col_scan_kernel(int* __restrict__ hist2d, int* __restrict__ bcnt){
  __shared__ int s[NCHUNKS];
  int b = blockIdx.x, t = threadIdx.x;
  int v = hist2d[(size_t)t * NBMAX + b];
  s[t] = v; __syncthreads();
  #pragma unroll
  for (int off = 1; off < NCHUNKS; off <<= 1){
    int u = (t >= off) ? s[t - off] : 0;
    __syncthreads();
    s[t] += u;
    __syncthreads();
  }
  hist2d[(size_t)t * NBMAX + b] = s[t] - v;
  if (t == NCHUNKS - 1) bcnt[b] = s[t];
}

__global__ void scan_buckets_kernel(const int* __restrict__ bcnt, int nb, int total,
                                    int* __restrict__ bstart, int* __restrict__ row_start, int n){
  __shared__ int s[1024];
  int t = threadIdx.x;
  int v = (t < nb) ? bcnt[t] : 0;
  s[t] = v; __syncthreads();
  #pragma unroll
  for (int off = 1; off < 1024; off <<= 1){
    int u = (t >= off) ? s[t - off] : 0;
    __syncthreads();
    s[t] += u;
    __syncthreads();
  }
  bstart[t] = (t < nb) ? s[t] - v : total;
  if (t == 0){ bstart[NBMAX] = total; row_start[n] = total; }
}

// wev[d*4+h] = sum_c We1[d, h*8+c] * a_e1[h,c]
__global__ void wevec_kernel(const float* __restrict__ We, const float* __restrict__ ae,
                             float* __restrict__ wev){
  int i = threadIdx.x;
  if (i >= 32) return;
  int d = i >> 2, h = i & 3;
  float acc = 0.f;
  #pragma unroll
  for (int c = 0; c < 8; ++c) acc = fmaf(We[d * 32 + h * 8 + c], ae[h * 8 + c], acc);
  wev[d * 4 + h] = acc;
}

// multisplit: deterministic bases, no global atomics; stages one 16B record.
__global__ __launch_bounds__(MS_THREADS)
void multisplit_kernel(const int* __restrict__ ei, int E, int CH,
                       const float* __restrict__ eattr, const float* __restrict__ wev,
                       const int* __restrict__ bstart, const int* __restrict__ prefix2d,
                       int4* __restrict__ staged){
  __shared__ int s_hist[NBMAX];
  __shared__ int s_base[NBMAX];
  __shared__ float s_wev[32];
  int t = threadIdx.x, chunk = blockIdx.x;
  if (t < 32) s_wev[t] = wev[t];
  const int* pre = prefix2d + (size_t)chunk * NBMAX;
  for (int i = t; i < NBMAX; i += MS_THREADS){
    s_base[i] = bstart[i] + pre[i];
    s_hist[i] = 0;
  }
  __syncthreads();
  int lo = chunk * CH, hi = min(lo + CH, E);
  for (int e = lo + t; e < hi; e += MS_THREADS){
    int d = ei[E + e];
    int b = d >> W_SHIFT;
    const float4* ea = (const float4*)(eattr + (size_t)e * 8);
    float4 v0 = ea[0], v1 = ea[1];
    float av[8] = {v0.x, v0.y, v0.z, v0.w, v1.x, v1.y, v1.z, v1.w};
    float e0 = 0, e1 = 0, e2 = 0, e3 = 0;
    #pragma unroll
    for (int k = 0; k < 8; ++k){
      e0 = fmaf(av[k], s_wev[k * 4 + 0], e0);
      e1 = fmaf(av[k], s_wev[k * 4 + 1], e1);
      e2 = fmaf(av[k], s_wev[k * 4 + 2], e2);
      e3 = fmaf(av[k], s_wev[k * 4 + 3], e3);
    }
    __half2 h01 = __floats2half2_rn(e0, e1);
    __half2 h23 = __floats2half2_rn(e2, e3);
    int pos = s_base[b] + atomicAdd(&s_hist[b], 1);
    staged[pos] = make_int4(ei[e], d & (BUCKET_N - 1),
                            __builtin_bit_cast(int, h01), __builtin_bit_cast(int, h23));
  }
}

// per-bucket: counts -> row_start; permute staged to final CSR (recs 16B + srcs 4B);
// then 8-lane-per-node esc row sums from the L2-hot recs window -> selfesc. No f32 atomics.
__global__ __launch_bounds__(MS_THREADS)
void bucket_scatter_kernel(const int* __restrict__ bstart, const int4* __restrict__ staged,
                           int n, int* __restrict__ row_start, int4* __restrict__ recs,
                           int* __restrict__ srcs, float4* __restrict__ selfesc){
  __shared__ int s_cnt[BUCKET_N];
  __shared__ int s_cur[BUCKET_N];
  __shared__ int s_start[BUCKET_N];
  int b = blockIdx.x, t = threadIdx.x;
  int node0 = b << W_SHIFT;
  if (t < BUCKET_N) s_cnt[t] = 0;
  __syncthreads();
  int lo = bstart[b], hi = bstart[b + 1];
  for (int i = lo + t; i < hi; i += MS_THREADS)
    atomicAdd(&s_cnt[staged[i].y], 1);
  __syncthreads();
  if (t < BUCKET_N) s_cur[t] = s_cnt[t];
  __syncthreads();
  #pragma unroll
  for (int off = 1; off < BUCKET_N; off <<= 1){
    int v = (t < BUCKET_N && t >= off) ? s_cur[t - off] : 0;
    __syncthreads();
    if (t < BUCKET_N) s_cur[t] += v;
    __syncthreads();
  }
  if (t < BUCKET_N){
    int excl = s_cur[t] - s_cnt[t];
    int nd = node0 + t;
    if (nd <= n) row_start[nd] = lo + excl;
    s_start[t] = lo + excl;
    s_cur[t] = lo + excl;
  }
  __syncthreads();
  for (int i = lo + t; i < hi; i += MS_THREADS){
    int4 r = staged[i];
    int pos = atomicAdd(&s_cur[r.y], 1);
    recs[pos] = r;
    srcs[pos] = r.x;
  }
  __syncthreads();
  // selfesc: 8 lanes per node, rows are L2-hot (just written by this block)
  int nl = t >> 3, sub = t & 7;
  int nd2 = node0 + nl;
  if (nd2 >= n) return;
  int r0 = s_start[nl], r1 = s_start[nl] + s_cnt[nl];
  float e0 = 0, e1 = 0, e2 = 0, e3 = 0;
  for (int k = r0 + sub; k < r1; k += 8){
    int4 r = recs[k];
    float2 f01 = __half22float2(__builtin_bit_cast(__half2, r.z));
    float2 f23 = __half22float2(__builtin_bit_cast(__half2, r.w));
    e0 += f01.x; e1 += f01.y; e2 += f23.x; e3 += f23.y;
  }
  #pragma unroll
  for (int off = 1; off < 8; off <<= 1){
    e0 += __shfl_xor(e0, off, 64); e1 += __shfl_xor(e1, off, 64);
    e2 += __shfl_xor(e2, off, 64); e3 += __shfl_xor(e3, off, 64);
  }
  if (sub == 0){
    float inv = 1.f / fmaxf((float)s_cnt[nl], 1.f);
    selfesc[nd2] = make_float4(e0 * inv, e1 * inv, e2 * inv, e3 * inv);
  }
}

// ---------------- fused node transform + attention pre-scores ----------------
template<int K, int M, int C>
__global__ void gemm_score_kernel(const float* __restrict__ A, const float* __restrict__ W,
                                  const float* __restrict__ asrc, const float* __restrict__ adst,
                                  float* __restrict__ out, float* __restrict__ sS,
                                  float* __restrict__ sD, int n){
  __shared__ float Ws[K * M];
  __shared__ float s_as[M], s_ad[M];
  for (int i = threadIdx.x; i < K * M; i += blockDim.x) Ws[i] = W[i];
  if (threadIdx.x < M){ s_as[threadIdx.x] = asrc[threadIdx.x]; s_ad[threadIdx.x] = adst[threadIdx.x]; }
  __syncthreads();
  constexpr int ROWS = 256 / M;
  int row = blockIdx.x * ROWS + (int)threadIdx.x / M;
  int col = (int)threadIdx.x % M;
  if (row >= n) return;
  const float4* a4 = (const float4*)(A + (size_t)row * K);
  float acc = 0.f;
  #pragma unroll
  for (int k4 = 0; k4 < K / 4; ++k4){
    float4 av = a4[k4];
    acc = fmaf(av.x, Ws[(k4 * 4 + 0) * M + col], acc);
    acc = fmaf(av.y, Ws[(k4 * 4 + 1) * M + col], acc);
    acc = fmaf(av.z, Ws[(k4 * 4 + 2) * M + col], acc);
    acc = fmaf(av.w, Ws[(k4 * 4 + 3) * M + col], acc);
  }
  out[(size_t)row * M + col] = acc;
  float ps = acc * s_as[col], pd = acc * s_ad[col];
  #pragma unroll
  for (int off = 1; off < C; off <<= 1){
    ps += __shfl_xor(ps, off, 64);
    pd += __shfl_xor(pd, off, 64);
  }
  if ((col & (C - 1)) == 0){
    int h = col / C;
    sS[(size_t)row * 4 + h] = ps;
    sD[(size_t)row * 4 + h] = pd;
  }
}

// ---------------- CSR gather-aggregate ----------------
// MODE 0: concat heads + bias + ELU (layer1, OUT=32), EDGE: esc fp16x4 + selfesc
// MODE 1: mean heads + bias + ELU   (layer2, OUT=32) — srcs-only stream
// MODE 2: mean heads + bias         (layer3, OUT=4) — lane-per-edge, srcs-only
template<int MODE, bool EDGE>
__global__ void gather_kernel(const int* __restrict__ row_start, const int4* __restrict__ recs,
                              const int* __restrict__ srcs, const float4* __restrict__ selfesc,
                              const float* __restrict__ sS, const float* __restrict__ sD,
                              const float* __restrict__ xh, const float* __restrict__ bias,
                              float* __restrict__ out, int n){
  int wv = threadIdx.x >> 6, lane = threadIdx.x & 63;
  int node = blockIdx.x * 4 + wv;

  if constexpr (MODE == 2){
    if (node >= n) return;
    int rs = row_start[node], deg = row_start[node + 1] - rs;
    float4 sd4 = ((const float4*)sD)[node];
    float4 acc = {0,0,0,0}, dsum = {0,0,0,0};
    for (int k = lane; k < deg; k += 64){
      int s = srcs[rs + k];
      float4 ss = ((const float4*)sS)[s];
      float4 w;
      w.x = fexp(lrelu(ss.x + sd4.x)); w.y = fexp(lrelu(ss.y + sd4.y));
      w.z = fexp(lrelu(ss.z + sd4.z)); w.w = fexp(lrelu(ss.w + sd4.w));
      dsum.x += w.x; dsum.y += w.y; dsum.z += w.z; dsum.w += w.w;
      float4 xv = ((const float4*)xh)[s];
      acc.x = fmaf(w.x, xv.x, acc.x); acc.y = fmaf(w.y, xv.y, acc.y);
      acc.z = fmaf(w.z, xv.z, acc.z); acc.w = fmaf(w.w, xv.w, acc.w);
    }
    #pragma unroll
    for (int off = 1; off < 64; off <<= 1){
      acc.x += __shfl_xor(acc.x, off, 64); acc.y += __shfl_xor(acc.y, off, 64);
      acc.z += __shfl_xor(acc.z, off, 64); acc.w += __shfl_xor(acc.w, off, 64);
      dsum.x += __shfl_xor(dsum.x, off, 64); dsum.y += __shfl_xor(dsum.y, off, 64);
      dsum.z += __shfl_xor(dsum.z, off, 64); dsum.w += __shfl_xor(dsum.w, off, 64);
    }
    if (lane == 0){
      float4 ssn = ((const float4*)sS)[node];
      float4 wsf;
      wsf.x = fexp(lrelu(ssn.x + sd4.x)); wsf.y = fexp(lrelu(ssn.y + sd4.y));
      wsf.z = fexp(lrelu(ssn.z + sd4.z)); wsf.w = fexp(lrelu(ssn.w + sd4.w));
      float4 xvn = ((const float4*)xh)[node];
      float v = (acc.x + wsf.x * xvn.x) / (dsum.x + wsf.x + 1e-16f)
              + (acc.y + wsf.y * xvn.y) / (dsum.y + wsf.y + 1e-16f)
              + (acc.z + wsf.z * xvn.z) / (dsum.z + wsf.z + 1e-16f)
              + (acc.w + wsf.w * xvn.w) / (dsum.w + wsf.w + 1e-16f);
      out[node] = 0.25f * v + bias[0];
    }
    return;
  } else {
  __shared__ float4 s_w[4][64];
  __shared__ int    s_src[4][64];
  if (node >= n) return;
  int rs = row_start[node], deg = row_start[node + 1] - rs;
  float4 sd4 = ((const float4*)sD)[node];
  int q = lane & 7;          // float4 column of the 32-wide row
  int h = q >> 1;            // head for this column group
  int sg = lane >> 3;        // slot group (8 edges per phase-2 slot set)
  float4 acc = {0,0,0,0};
  float dacc = 0.f;          // this lane's head denominator (partial)

  for (int base = 0; base < deg; base += 64){
    int k = base + lane;
    float4 w = {0,0,0,0}; int s = 0;
    if (k < deg){
      float a0, a1, a2, a3;
      if constexpr (EDGE){
        int4 rec = recs[rs + k];
        s = rec.x;
        float4 ss = ((const float4*)sS)[s];
        float2 f01 = __half22float2(__builtin_bit_cast(__half2, rec.z));
        float2 f23 = __half22float2(__builtin_bit_cast(__half2, rec.w));
        a0 = ss.x + sd4.x + f01.x; a1 = ss.y + sd4.y + f01.y;
        a2 = ss.z + sd4.z + f23.x; a3 = ss.w + sd4.w + f23.y;
      } else {
        s = srcs[rs + k];
        float4 ss = ((const float4*)sS)[s];
        a0 = ss.x + sd4.x; a1 = ss.y + sd4.y;
        a2 = ss.z + sd4.z; a3 = ss.w + sd4.w;
      }
      w.x = fexp(lrelu(a0)); w.y = fexp(lrelu(a1));
      w.z = fexp(lrelu(a2)); w.w = fexp(lrelu(a3));
    }
    s_w[wv][lane] = w;
    s_src[wv][lane] = s;
    WAVE_FENCE();
    int nvalid = min(deg - base, 64);
    const float* s_wf = (const float*)&s_w[wv][0];
    #pragma unroll
    for (int i = 0; i < 8; ++i){
      int slot = i * 8 + sg;
      if (slot < nvalid){
        int s2 = s_src[wv][slot];
        float wg = s_wf[slot * 4 + h];
        float4 xv = ((const float4*)xh)[(size_t)s2 * 8 + q];
        dacc += wg;
        acc.x = fmaf(wg, xv.x, acc.x); acc.y = fmaf(wg, xv.y, acc.y);
        acc.z = fmaf(wg, xv.z, acc.z); acc.w = fmaf(wg, xv.w, acc.w);
      }
    }
    WAVE_FENCE();
  }

  // combine the 8 slot-group partials (acc + denominator together)
  #pragma unroll
  for (int off = 8; off < 64; off <<= 1){
    acc.x += __shfl_xor(acc.x, off, 64); acc.y += __shfl_xor(acc.y, off, 64);
    acc.z += __shfl_xor(acc.z, off, 64); acc.w += __shfl_xor(acc.w, off, 64);
    dacc  += __shfl_xor(dacc,  off, 64);
  }
  // self-loop: alpha = sS[node]+sD[node] (+ precomputed mean esc for layer 1)
  float4 ssn = ((const float4*)sS)[node];
  float a_self = sel4(ssn, h) + sel4(sd4, h);
  if constexpr (EDGE) a_self += sel4(selfesc[node], h);
  float wsel = fexp(lrelu(a_self));
  float4 xvn = ((const float4*)xh)[(size_t)node * 8 + q];
  acc.x = fmaf(wsel, xvn.x, acc.x); acc.y = fmaf(wsel, xvn.y, acc.y);
  acc.z = fmaf(wsel, xvn.z, acc.z); acc.w = fmaf(wsel, xvn.w, acc.w);
  dacc += wsel;
  float rin = 1.f / (dacc + 1e-16f);
  float4 val = {acc.x * rin, acc.y * rin, acc.z * rin, acc.w * rin};

  if constexpr (MODE == 0){
    float4 b4 = ((const float4*)bias)[q];
    val.x = elu1(val.x + b4.x); val.y = elu1(val.y + b4.y);
    val.z = elu1(val.z + b4.z); val.w = elu1(val.w + b4.w);
    if (lane < 8) ((float4*)out)[(size_t)node * 8 + lane] = val;
  } else {
    val.x += __shfl_xor(val.x, 2, 64); val.y += __shfl_xor(val.y, 2, 64);
    val.z += __shfl_xor(val.z, 2, 64); val.w += __shfl_xor(val.w, 2, 64);
    val.x += __shfl_xor(val.x, 4, 64); val.y += __shfl_xor(val.y, 4, 64);
    val.z += __shfl_xor(val.z, 4, 64); val.w += __shfl_xor(val.w, 4, 64);
    float4 b4 = ((const float4*)bias)[q & 1];
    val.x = elu1(val.x * 0.25f + b4.x); val.y = elu1(val.y * 0.25f + b4.y);
    val.z = elu1(val.z * 0.25f + b4.z); val.w = elu1(val.w * 0.25f + b4.w);
    if (lane < 2) ((float4*)out)[(size_t)node * 2 + lane] = val;
  }
  }
}

// ---------------- launcher ----------------

extern "C" void kernel_launch(void* const* d_in, const int* in_sizes, int n_in,
                              void* d_out, int out_size, void* d_ws, size_t ws_size,
                              hipStream_t stream){
  const float* x     = (const float*)d_in[0];
  const float* eattr = (const float*)d_in[1];
  const int*   ei    = (const int*)d_in[2];
  const float* W1  = (const float*)d_in[3];
  const float* as1 = (const float*)d_in[4];
  const float* ad1 = (const float*)d_in[5];
  const float* We1 = (const float*)d_in[6];
  const float* ae1 = (const float*)d_in[7];
  const float* b1  = (const float*)d_in[8];
  const float* W2  = (const float*)d_in[9];
  const float* as2 = (const float*)d_in[10];
  const float* ad2 = (const float*)d_in[11];
  const float* b2  = (const float*)d_in[12];
  const float* W3  = (const float*)d_in[13];
  const float* as3 = (const float*)d_in[14];
  const float* ad3 = (const float*)d_in[15];
  const float* b3  = (const float*)d_in[16];

  const int N = in_sizes[0] / 128;
  const int E = in_sizes[2] / 2;
  const int nb_buckets = (N + BUCKET_N - 1) >> W_SHIFT;   // 782 for N=100000
  const int CH = cdiv(E, NCHUNKS);

  // layout: [staged int4 E | recs int4 E | srcs int E | hist2d | selfesc | ints]
  // floats (xh,sS,sD,h1,h2 = N*320 B = 32 MB) alias the staged region
  // (E*16 = 51.2 MB); staged is dead before the first gemm writes xh.
  char* b0 = (char*)d_ws;
  int4* staged = (int4*)b0;
  float* fp = (float*)b0;
  float* xh = fp; fp += (size_t)N * 32;
  float* sS = fp; fp += (size_t)N * 4;
  float* sD = fp; fp += (size_t)N * 4;
  float* h1 = fp; fp += (size_t)N * 32;
  float* h2 = fp; fp += (size_t)N * 8;
  int4* recs = (int4*)(b0 + (size_t)E * 16);
  int*  srcs = (int*)(b0 + (size_t)E * 32);
  int* hist2d = (int*)(b0 + (size_t)E * 36);
  float4* selfesc = (float4*)(hist2d + (size_t)NCHUNKS * NBMAX);
  int* ip = (int*)(selfesc + N);
  int* bcnt      = ip; ip += NBMAX;
  int* bstart    = ip; ip += NBMAX + 1;
  int* row_start = ip; ip += N + 1;
  float* wev = (float*)ip;

  const int B = 256;

  // ---- CSR build: plan (no global atomics) -> multisplit -> bucket scatter ----
  wevec_kernel<<<1, 32, 0, stream>>>(We1, ae1, wev);
  hist_chunks_kernel<<<NCHUNKS, MS_THREADS, 0, stream>>>(ei, E, CH, hist2d);
  col_scan_kernel<<<nb_buckets, NCHUNKS, 0, stream>>>(hist2d, bcnt);
  scan_buckets_kernel<<<1, 1024, 0, stream>>>(bcnt, nb_buckets, E, bstart, row_start, N);
  multisplit_kernel<<<NCHUNKS, MS_THREADS, 0, stream>>>(ei, E, CH, eattr, wev, bstart, hist2d, staged);
  bucket_scatter_kernel<<<nb_buckets, MS_THREADS, 0, stream>>>(bstart, staged, N, row_start, recs, srcs, selfesc);

  // ---- layer 1: 128 -> 4x8, concat, edge scores ----
  gemm_score_kernel<128,32,8><<<cdiv(N, 8), B, 0, stream>>>(x, W1, as1, ad1, xh, sS, sD, N);
  gather_kernel<0,true><<<cdiv(N, 4), B, 0, stream>>>(row_start, recs, srcs, selfesc, sS, sD, xh, b1, h1, N);

  // ---- layer 2: 32 -> 4x8, mean heads ----
  gemm_score_kernel<32,32,8><<<cdiv(N, 8), B, 0, stream>>>(h1, W2, as2, ad2, xh, sS, sD, N);
  gather_kernel<1,false><<<cdiv(N, 4), B, 0, stream>>>(row_start, recs, srcs, selfesc, sS, sD, xh, b2, h2, N);

  // ---- layer 3: 8 -> 4x1, mean heads ----
  gemm_score_kernel<8,4,1><<<cdiv(N, 64), B, 0, stream>>>(h2, W3, as3, ad3, xh, sS, sD, N);
  gather_kernel<2,false><<<cdiv(N, 4), B, 0, stream>>>(row_start, recs, srcs, selfesc, sS, sD, xh, b3, (float*)d_out, N);
}

// Round 12
// 433.634 us; speedup vs baseline: 1.2076x; 1.0713x over previous
//
#include <hip/hip_runtime.h>
#include <hip/hip_fp16.h>
#include <cmath>

static inline int cdiv(long a, int b){ return (int)((a + b - 1) / b); }

__device__ __forceinline__ float lrelu(float x){ return x > 0.f ? x : 0.2f * x; }
__device__ __forceinline__ float elu1(float x){ return x > 0.f ? x : expm1f(x); }
__device__ __forceinline__ float fexp(float x){ return __expf(x); }   // native v_exp path
__device__ __forceinline__ float sel4(float4 v, int h){
  float ab = (h & 1) ? v.y : v.x;
  float cd = (h & 1) ? v.w : v.z;
  return (h & 2) ? cd : ab;
}

// compiler-level fence: keep LDS writes (phase1) before LDS reads (phase2)
// within the same wave; HW DS pipe is in-order per wave.
#define WAVE_FENCE() do { asm volatile("" ::: "memory"); __builtin_amdgcn_sched_barrier(0); } while(0)

#define W_SHIFT 7                 // 128 nodes per bucket
#define BUCKET_N (1 << W_SHIFT)
#define NBMAX   1024              // >= number of buckets (782)
#define NCHUNKS 1024              // chunks; also col_scan thread count
#define CH_MAX  3136              // max edges per chunk (E/NCHUNKS = 3125 for E=3.2M)
#define MS_THREADS 1024

// staged record: {src, dst(full), esc01(fp16x2), esc23(fp16x2)}

// ---------------- CSR build (atomic-free scheduling) ----------------

__global__ __launch_bounds__(MS_THREADS)
void hist_chunks_kernel(const int* __restrict__ ei, int E, int CH, int* __restrict__ hist2d){
  __shared__ int s_b[NBMAX];
  int t = threadIdx.x, chunk = blockIdx.x;
  s_b[t] = 0;
  __syncthreads();
  int lo = chunk * CH, hi = min(lo + CH, E);
  for (int e = lo + t; e < hi; e += MS_THREADS)
    atomicAdd(&s_b[ei[E + e] >> W_SHIFT], 1);
  __syncthreads();
  hist2d[(size_t)chunk * NBMAX + t] = s_b[t];
}

// per bucket: exclusive prefix over chunks (in place), total -> bcnt
__global__ __launch_bounds__(NCHUNKS)
void col_scan_kernel(int* __restrict__ hist2d, int* __restrict__ bcnt){
  __shared__ int s[NCHUNKS];
  int b = blockIdx.x, t = threadIdx.x;
  int v = hist2d[(size_t)t * NBMAX + b];
  s[t] = v; __syncthreads();
  #pragma unroll
  for (int off = 1; off < NCHUNKS; off <<= 1){
    int u = (t >= off) ? s[t - off] : 0;
    __syncthreads();
    s[t] += u;
    __syncthreads();
  }
  hist2d[(size_t)t * NBMAX + b] = s[t] - v;
  if (t == NCHUNKS - 1) bcnt[b] = s[t];
}

__global__ void scan_buckets_kernel(const int* __restrict__ bcnt, int nb, int total,
                                    int* __restrict__ bstart, int* __restrict__ row_start, int n){
  __shared__ int s[1024];
  int t = threadIdx.x;
  int v = (t < nb) ? bcnt[t] : 0;
  s[t] = v; __syncthreads();
  #pragma unroll
  for (int off = 1; off < 1024; off <<= 1){
    int u = (t >= off) ? s[t - off] : 0;
    __syncthreads();
    s[t] += u;
    __syncthreads();
  }
  bstart[t] = (t < nb) ? s[t] - v : total;
  if (t == 0){ bstart[NBMAX] = total; row_start[n] = total; }
}

// wev[d*4+h] = sum_c We1[d, h*8+c] * a_e1[h,c]
__global__ void wevec_kernel(const float* __restrict__ We, const float* __restrict__ ae,
                             float* __restrict__ wev){
  int i = threadIdx.x;
  if (i >= 32) return;
  int d = i >> 2, h = i & 3;
  float acc = 0.f;
  #pragma unroll
  for (int c = 0; c < 8; ++c) acc = fmaf(We[d * 32 + h * 8 + c], ae[h * 8 + c], acc);
  wev[d * 4 + h] = acc;
}

// multisplit v2: sort the whole chunk by bucket in LDS, then copy out densely.
// Deterministic global bases (bstart + per-chunk prefix) -> no global atomics.
__global__ __launch_bounds__(MS_THREADS)
void multisplit_kernel(const int* __restrict__ ei, int E, int CH,
                       const float* __restrict__ eattr, const float* __restrict__ wev,
                       const int* __restrict__ bstart, const int* __restrict__ prefix2d,
                       int4* __restrict__ staged){
  __shared__ int4 s_rec[CH_MAX];        // 50.2 KB
  __shared__ int s_fill[NBMAX];
  __shared__ int s_lbase[NBMAX];
  __shared__ int s_shift[NBMAX];
  __shared__ float s_wev[32];
  int t = threadIdx.x, chunk = blockIdx.x;
  if (t < 32) s_wev[t] = wev[t];
  s_fill[t] = 0;                        // MS_THREADS == NBMAX
  __syncthreads();
  int lo = chunk * CH, hi = min(lo + CH, E);
  int cnt = hi - lo;
  for (int e = lo + t; e < hi; e += MS_THREADS)
    atomicAdd(&s_fill[ei[E + e] >> W_SHIFT], 1);
  __syncthreads();
  // block-wide exclusive scan of s_fill (1024 bins, 1024 threads)
  int v = s_fill[t];
  s_lbase[t] = v; __syncthreads();
  #pragma unroll
  for (int off = 1; off < NBMAX; off <<= 1){
    int u = (t >= off) ? s_lbase[t - off] : 0;
    __syncthreads();
    s_lbase[t] += u;
    __syncthreads();
  }
  int excl = s_lbase[t] - v;
  s_lbase[t] = excl;                    // own cell only; barrier follows
  s_shift[t] = bstart[t] + prefix2d[(size_t)chunk * NBMAX + t] - excl;
  s_fill[t] = 0;
  __syncthreads();
  // place records into LDS in bucket-sorted order
  for (int e = lo + t; e < hi; e += MS_THREADS){
    int d = ei[E + e];
    int b = d >> W_SHIFT;
    const float4* ea = (const float4*)(eattr + (size_t)e * 8);
    float4 v0 = ea[0], v1 = ea[1];
    float av[8] = {v0.x, v0.y, v0.z, v0.w, v1.x, v1.y, v1.z, v1.w};
    float e0 = 0, e1 = 0, e2 = 0, e3 = 0;
    #pragma unroll
    for (int k = 0; k < 8; ++k){
      e0 = fmaf(av[k], s_wev[k * 4 + 0], e0);
      e1 = fmaf(av[k], s_wev[k * 4 + 1], e1);
      e2 = fmaf(av[k], s_wev[k * 4 + 2], e2);
      e3 = fmaf(av[k], s_wev[k * 4 + 3], e3);
    }
    __half2 h01 = __floats2half2_rn(e0, e1);
    __half2 h23 = __floats2half2_rn(e2, e3);
    int pos = s_lbase[b] + atomicAdd(&s_fill[b], 1);
    s_rec[pos] = make_int4(ei[e], d,
                           __builtin_bit_cast(int, h01), __builtin_bit_cast(int, h23));
  }
  __syncthreads();
  // dense copy-out: consecutive threads -> mostly-consecutive global addresses
  for (int i = t; i < cnt; i += MS_THREADS){
    int4 r = s_rec[i];
    staged[s_shift[r.y >> W_SHIFT] + i] = r;
  }
}

// per-bucket: counts -> row_start; permute staged to final CSR (srcs 4B + escp 8B);
// then 8-lane-per-node esc row sums from the L2-hot escp window -> selfesc.
__global__ __launch_bounds__(MS_THREADS)
void bucket_scatter_kernel(const int* __restrict__ bstart, const int4* __restrict__ staged,
                           int n, int* __restrict__ row_start, int* __restrict__ srcs,
                           uint2* __restrict__ escp, float4* __restrict__ selfesc){
  __shared__ int s_cnt[BUCKET_N];
  __shared__ int s_cur[BUCKET_N];
  __shared__ int s_start[BUCKET_N];
  int b = blockIdx.x, t = threadIdx.x;
  int node0 = b << W_SHIFT;
  if (t < BUCKET_N) s_cnt[t] = 0;
  __syncthreads();
  int lo = bstart[b], hi = bstart[b + 1];
  for (int i = lo + t; i < hi; i += MS_THREADS)
    atomicAdd(&s_cnt[staged[i].y & (BUCKET_N - 1)], 1);
  __syncthreads();
  if (t < BUCKET_N) s_cur[t] = s_cnt[t];
  __syncthreads();
  #pragma unroll
  for (int off = 1; off < BUCKET_N; off <<= 1){
    int v = (t < BUCKET_N && t >= off) ? s_cur[t - off] : 0;
    __syncthreads();
    if (t < BUCKET_N) s_cur[t] += v;
    __syncthreads();
  }
  if (t < BUCKET_N){
    int excl = s_cur[t] - s_cnt[t];
    int nd = node0 + t;
    if (nd <= n) row_start[nd] = lo + excl;
    s_start[t] = lo + excl;
    s_cur[t] = lo + excl;
  }
  __syncthreads();
  for (int i = lo + t; i < hi; i += MS_THREADS){
    int4 r = staged[i];
    int pos = atomicAdd(&s_cur[r.y & (BUCKET_N - 1)], 1);
    srcs[pos] = r.x;
    escp[pos] = make_uint2((unsigned)r.z, (unsigned)r.w);
  }
  __syncthreads();
  // selfesc: 8 lanes per node, rows are L2-hot (just written by this block)
  int nl = t >> 3, sub = t & 7;
  int nd2 = node0 + nl;
  if (nd2 >= n) return;
  int r0 = s_start[nl], r1 = s_start[nl] + s_cnt[nl];
  float e0 = 0, e1 = 0, e2 = 0, e3 = 0;
  for (int k = r0 + sub; k < r1; k += 8){
    uint2 u = escp[k];
    float2 f01 = __half22float2(__builtin_bit_cast(__half2, u.x));
    float2 f23 = __half22float2(__builtin_bit_cast(__half2, u.y));
    e0 += f01.x; e1 += f01.y; e2 += f23.x; e3 += f23.y;
  }
  #pragma unroll
  for (int off = 1; off < 8; off <<= 1){
    e0 += __shfl_xor(e0, off, 64); e1 += __shfl_xor(e1, off, 64);
    e2 += __shfl_xor(e2, off, 64); e3 += __shfl_xor(e3, off, 64);
  }
  if (sub == 0){
    float inv = 1.f / fmaxf((float)s_cnt[nl], 1.f);
    selfesc[nd2] = make_float4(e0 * inv, e1 * inv, e2 * inv, e3 * inv);
  }
}

// ---------------- fused node transform + attention pre-scores ----------------
template<int K, int M, int C>
__global__ void gemm_score_kernel(const float* __restrict__ A, const float* __restrict__ W,
                                  const float* __restrict__ asrc, const float* __restrict__ adst,
                                  float* __restrict__ out, float* __restrict__ sS,
                                  float* __restrict__ sD, int n){
  __shared__ float Ws[K * M];
  __shared__ float s_as[M], s_ad[M];
  for (int i = threadIdx.x; i < K * M; i += blockDim.x) Ws[i] = W[i];
  if (threadIdx.x < M){ s_as[threadIdx.x] = asrc[threadIdx.x]; s_ad[threadIdx.x] = adst[threadIdx.x]; }
  __syncthreads();
  constexpr int ROWS = 256 / M;
  int row = blockIdx.x * ROWS + (int)threadIdx.x / M;
  int col = (int)threadIdx.x % M;
  if (row >= n) return;
  const float4* a4 = (const float4*)(A + (size_t)row * K);
  float acc = 0.f;
  #pragma unroll
  for (int k4 = 0; k4 < K / 4; ++k4){
    float4 av = a4[k4];
    acc = fmaf(av.x, Ws[(k4 * 4 + 0) * M + col], acc);
    acc = fmaf(av.y, Ws[(k4 * 4 + 1) * M + col], acc);
    acc = fmaf(av.z, Ws[(k4 * 4 + 2) * M + col], acc);
    acc = fmaf(av.w, Ws[(k4 * 4 + 3) * M + col], acc);
  }
  out[(size_t)row * M + col] = acc;
  float ps = acc * s_as[col], pd = acc * s_ad[col];
  #pragma unroll
  for (int off = 1; off < C; off <<= 1){
    ps += __shfl_xor(ps, off, 64);
    pd += __shfl_xor(pd, off, 64);
  }
  if ((col & (C - 1)) == 0){
    int h = col / C;
    sS[(size_t)row * 4 + h] = ps;
    sD[(size_t)row * 4 + h] = pd;
  }
}

// ---------------- CSR gather-aggregate ----------------
// MODE 0: concat heads + bias + ELU (layer1, OUT=32), EDGE: escp fp16x4 + selfesc
// MODE 1: mean heads + bias + ELU + FUSED layer-3 prep (xh3/sS3/sD3); no h2 store
// MODE 2: mean heads + bias         (layer3, OUT=4) — lane-per-edge path
template<int MODE, bool EDGE>
__global__ void gather_kernel(const int* __restrict__ row_start, const int* __restrict__ srcs,
                              const uint2* __restrict__ escp, const float4* __restrict__ selfesc,
                              const float* __restrict__ sS, const float* __restrict__ sD,
                              const float* __restrict__ xh, const float* __restrict__ bias,
                              float* __restrict__ out, int n,
                              const float* __restrict__ W3p, const float* __restrict__ as3p,
                              const float* __restrict__ ad3p, float* __restrict__ xh3,
                              float* __restrict__ ss3, float* __restrict__ sd3){
  int wv = threadIdx.x >> 6, lane = threadIdx.x & 63;
  int node = blockIdx.x * 4 + wv;

  if constexpr (MODE == 2){
    if (node >= n) return;
    int rs = row_start[node], deg = row_start[node + 1] - rs;
    float4 sd4 = ((const float4*)sD)[node];
    float4 acc = {0,0,0,0}, dsum = {0,0,0,0};
    for (int k = lane; k < deg; k += 64){
      int s = srcs[rs + k];
      float4 ss = ((const float4*)sS)[s];
      float4 w;
      w.x = fexp(lrelu(ss.x + sd4.x)); w.y = fexp(lrelu(ss.y + sd4.y));
      w.z = fexp(lrelu(ss.z + sd4.z)); w.w = fexp(lrelu(ss.w + sd4.w));
      dsum.x += w.x; dsum.y += w.y; dsum.z += w.z; dsum.w += w.w;
      float4 xv = ((const float4*)xh)[s];
      acc.x = fmaf(w.x, xv.x, acc.x); acc.y = fmaf(w.y, xv.y, acc.y);
      acc.z = fmaf(w.z, xv.z, acc.z); acc.w = fmaf(w.w, xv.w, acc.w);
    }
    #pragma unroll
    for (int off = 1; off < 64; off <<= 1){
      acc.x += __shfl_xor(acc.x, off, 64); acc.y += __shfl_xor(acc.y, off, 64);
      acc.z += __shfl_xor(acc.z, off, 64); acc.w += __shfl_xor(acc.w, off, 64);
      dsum.x += __shfl_xor(dsum.x, off, 64); dsum.y += __shfl_xor(dsum.y, off, 64);
      dsum.z += __shfl_xor(dsum.z, off, 64); dsum.w += __shfl_xor(dsum.w, off, 64);
    }
    if (lane == 0){
      float4 ssn = ((const float4*)sS)[node];
      float4 wsf;
      wsf.x = fexp(lrelu(ssn.x + sd4.x)); wsf.y = fexp(lrelu(ssn.y + sd4.y));
      wsf.z = fexp(lrelu(ssn.z + sd4.z)); wsf.w = fexp(lrelu(ssn.w + sd4.w));
      float4 xvn = ((const float4*)xh)[node];
      float v = (acc.x + wsf.x * xvn.x) / (dsum.x + wsf.x + 1e-16f)
              + (acc.y + wsf.y * xvn.y) / (dsum.y + wsf.y + 1e-16f)
              + (acc.z + wsf.z * xvn.z) / (dsum.z + wsf.z + 1e-16f)
              + (acc.w + wsf.w * xvn.w) / (dsum.w + wsf.w + 1e-16f);
      out[node] = 0.25f * v + bias[0];
    }
    return;
  } else {
  __shared__ float4 s_w[4][64];
  __shared__ int    s_src[4][64];
  __shared__ float  s_w3[32];
  __shared__ float  s_a3[8];
  if constexpr (MODE == 1){
    if (threadIdx.x < 32) s_w3[threadIdx.x] = W3p[threadIdx.x];
    if (threadIdx.x < 8)
      s_a3[threadIdx.x] = (threadIdx.x < 4) ? as3p[threadIdx.x] : ad3p[threadIdx.x - 4];
    __syncthreads();
  }
  if (node >= n) return;
  int rs = row_start[node], deg = row_start[node + 1] - rs;
  float4 sd4 = ((const float4*)sD)[node];
  int q = lane & 7;          // float4 column of the 32-wide row
  int h = q >> 1;            // head for this column group
  int sg = lane >> 3;        // slot group (8 edges per phase-2 slot set)
  float4 acc = {0,0,0,0};
  float dacc = 0.f;

  for (int base = 0; base < deg; base += 64){
    int k = base + lane;
    float4 w = {0,0,0,0}; int s = 0;
    if (k < deg){
      s = srcs[rs + k];
      float4 ss = ((const float4*)sS)[s];
      float a0 = ss.x + sd4.x, a1 = ss.y + sd4.y, a2 = ss.z + sd4.z, a3 = ss.w + sd4.w;
      if constexpr (EDGE){
        uint2 u = escp[rs + k];
        float2 f01 = __half22float2(__builtin_bit_cast(__half2, u.x));
        float2 f23 = __half22float2(__builtin_bit_cast(__half2, u.y));
        a0 += f01.x; a1 += f01.y; a2 += f23.x; a3 += f23.y;
      }
      w.x = fexp(lrelu(a0)); w.y = fexp(lrelu(a1));
      w.z = fexp(lrelu(a2)); w.w = fexp(lrelu(a3));
    }
    s_w[wv][lane] = w;
    s_src[wv][lane] = s;
    WAVE_FENCE();
    int nvalid = min(deg - base, 64);
    const float* s_wf = (const float*)&s_w[wv][0];
    #pragma unroll
    for (int i = 0; i < 8; ++i){
      int slot = i * 8 + sg;
      if (slot < nvalid){
        int s2 = s_src[wv][slot];
        float wg = s_wf[slot * 4 + h];
        float4 xv = ((const float4*)xh)[(size_t)s2 * 8 + q];
        dacc += wg;
        acc.x = fmaf(wg, xv.x, acc.x); acc.y = fmaf(wg, xv.y, acc.y);
        acc.z = fmaf(wg, xv.z, acc.z); acc.w = fmaf(wg, xv.w, acc.w);
      }
    }
    WAVE_FENCE();
  }

  #pragma unroll
  for (int off = 8; off < 64; off <<= 1){
    acc.x += __shfl_xor(acc.x, off, 64); acc.y += __shfl_xor(acc.y, off, 64);
    acc.z += __shfl_xor(acc.z, off, 64); acc.w += __shfl_xor(acc.w, off, 64);
    dacc  += __shfl_xor(dacc,  off, 64);
  }
  float4 ssn = ((const float4*)sS)[node];
  float a_self = sel4(ssn, h) + sel4(sd4, h);
  if constexpr (EDGE) a_self += sel4(selfesc[node], h);
  float wsel = fexp(lrelu(a_self));
  float4 xvn = ((const float4*)xh)[(size_t)node * 8 + q];
  acc.x = fmaf(wsel, xvn.x, acc.x); acc.y = fmaf(wsel, xvn.y, acc.y);
  acc.z = fmaf(wsel, xvn.z, acc.z); acc.w = fmaf(wsel, xvn.w, acc.w);
  dacc += wsel;
  float rin = 1.f / (dacc + 1e-16f);
  float4 val = {acc.x * rin, acc.y * rin, acc.z * rin, acc.w * rin};

  if constexpr (MODE == 0){
    float4 b4 = ((const float4*)bias)[q];
    val.x = elu1(val.x + b4.x); val.y = elu1(val.y + b4.y);
    val.z = elu1(val.z + b4.z); val.w = elu1(val.w + b4.w);
    if (lane < 8) ((float4*)out)[(size_t)node * 8 + lane] = val;
  } else {
    // mean over heads -> h2 (comps (q&1)*4+c), then fused layer-3 prep
    val.x += __shfl_xor(val.x, 2, 64); val.y += __shfl_xor(val.y, 2, 64);
    val.z += __shfl_xor(val.z, 2, 64); val.w += __shfl_xor(val.w, 2, 64);
    val.x += __shfl_xor(val.x, 4, 64); val.y += __shfl_xor(val.y, 4, 64);
    val.z += __shfl_xor(val.z, 4, 64); val.w += __shfl_xor(val.w, 4, 64);
    float4 b4 = ((const float4*)bias)[q & 1];
    val.x = elu1(val.x * 0.25f + b4.x); val.y = elu1(val.y * 0.25f + b4.y);
    val.z = elu1(val.z * 0.25f + b4.z); val.w = elu1(val.w * 0.25f + b4.w);
    // exchange halves with q^1 partner to assemble full h2 row
    float4 oth;
    oth.x = __shfl_xor(val.x, 1, 64); oth.y = __shfl_xor(val.y, 1, 64);
    oth.z = __shfl_xor(val.z, 1, 64); oth.w = __shfl_xor(val.w, 1, 64);
    float h2v[8];
    if (q & 1){
      h2v[0] = oth.x; h2v[1] = oth.y; h2v[2] = oth.z; h2v[3] = oth.w;
      h2v[4] = val.x; h2v[5] = val.y; h2v[6] = val.z; h2v[7] = val.w;
    } else {
      h2v[0] = val.x; h2v[1] = val.y; h2v[2] = val.z; h2v[3] = val.w;
      h2v[4] = oth.x; h2v[5] = oth.y; h2v[6] = oth.z; h2v[7] = oth.w;
    }
    float x3[4];
    #pragma unroll
    for (int j = 0; j < 4; ++j){
      float a = 0.f;
      #pragma unroll
      for (int k = 0; k < 8; ++k) a = fmaf(h2v[k], s_w3[k * 4 + j], a);
      x3[j] = a;
    }
    if (lane == 0){
      ((float4*)xh3)[node] = make_float4(x3[0], x3[1], x3[2], x3[3]);
      ((float4*)ss3)[node] = make_float4(x3[0] * s_a3[0], x3[1] * s_a3[1],
                                         x3[2] * s_a3[2], x3[3] * s_a3[3]);
      ((float4*)sd3)[node] = make_float4(x3[0] * s_a3[4], x3[1] * s_a3[5],
                                         x3[2] * s_a3[6], x3[3] * s_a3[7]);
    }
  }
  }
}

// ---------------- launcher ----------------

extern "C" void kernel_launch(void* const* d_in, const int* in_sizes, int n_in,
                              void* d_out, int out_size, void* d_ws, size_t ws_size,
                              hipStream_t stream){
  const float* x     = (const float*)d_in[0];
  const float* eattr = (const float*)d_in[1];
  const int*   ei    = (const int*)d_in[2];
  const float* W1  = (const float*)d_in[3];
  const float* as1 = (const float*)d_in[4];
  const float* ad1 = (const float*)d_in[5];
  const float* We1 = (const float*)d_in[6];
  const float* ae1 = (const float*)d_in[7];
  const float* b1  = (const float*)d_in[8];
  const float* W2  = (const float*)d_in[9];
  const float* as2 = (const float*)d_in[10];
  const float* ad2 = (const float*)d_in[11];
  const float* b2  = (const float*)d_in[12];
  const float* W3  = (const float*)d_in[13];
  const float* as3 = (const float*)d_in[14];
  const float* ad3 = (const float*)d_in[15];
  const float* b3  = (const float*)d_in[16];

  const int N = in_sizes[0] / 128;
  const int E = in_sizes[2] / 2;
  const int nb_buckets = (N + BUCKET_N - 1) >> W_SHIFT;   // 782 for N=100000
  const int CH = cdiv(E, NCHUNKS);                        // 3125 (<= CH_MAX)

  // layout: [staged int4 E | srcs E*4 | escp E*8 | hist2d 4MB | selfesc | x3 bufs | ints]
  // floats (xh,sS,sD,h1 = N*288 B = 28.8 MB) alias staged (E*16 = 51.2 MB);
  // staged is dead before the first gemm writes xh.
  char* b0 = (char*)d_ws;
  int4* staged = (int4*)b0;
  float* fp = (float*)b0;
  float* xh = fp; fp += (size_t)N * 32;
  float* sS = fp; fp += (size_t)N * 4;
  float* sD = fp; fp += (size_t)N * 4;
  float* h1 = fp; fp += (size_t)N * 32;
  int*  srcs = (int*)(b0 + (size_t)E * 16);
  uint2* escp = (uint2*)(b0 + (size_t)E * 20);
  int* hist2d = (int*)(b0 + (size_t)E * 28);
  float4* selfesc = (float4*)(hist2d + (size_t)NCHUNKS * NBMAX);
  float* xh3 = (float*)(selfesc + N);
  float* ss3 = xh3 + (size_t)N * 4;
  float* sd3 = ss3 + (size_t)N * 4;
  int* ip = (int*)(sd3 + (size_t)N * 4);
  int* bcnt      = ip; ip += NBMAX;
  int* bstart    = ip; ip += NBMAX + 1;
  int* row_start = ip; ip += N + 1;
  float* wev = (float*)ip;

  const int B = 256;

  // ---- CSR build: plan (no global atomics) -> LDS-sorted multisplit -> bucket scatter ----
  wevec_kernel<<<1, 32, 0, stream>>>(We1, ae1, wev);
  hist_chunks_kernel<<<NCHUNKS, MS_THREADS, 0, stream>>>(ei, E, CH, hist2d);
  col_scan_kernel<<<nb_buckets, NCHUNKS, 0, stream>>>(hist2d, bcnt);
  scan_buckets_kernel<<<1, 1024, 0, stream>>>(bcnt, nb_buckets, E, bstart, row_start, N);
  multisplit_kernel<<<NCHUNKS, MS_THREADS, 0, stream>>>(ei, E, CH, eattr, wev, bstart, hist2d, staged);
  bucket_scatter_kernel<<<nb_buckets, MS_THREADS, 0, stream>>>(bstart, staged, N, row_start, srcs, escp, selfesc);

  // ---- layer 1: 128 -> 4x8, concat, edge scores ----
  gemm_score_kernel<128,32,8><<<cdiv(N, 8), B, 0, stream>>>(x, W1, as1, ad1, xh, sS, sD, N);
  gather_kernel<0,true><<<cdiv(N, 4), B, 0, stream>>>(row_start, srcs, escp, selfesc, sS, sD, xh, b1, h1, N,
                                                      nullptr, nullptr, nullptr, nullptr, nullptr, nullptr);

  // ---- layer 2: 32 -> 4x8, mean heads; fused layer-3 prep ----
  gemm_score_kernel<32,32,8><<<cdiv(N, 8), B, 0, stream>>>(h1, W2, as2, ad2, xh, sS, sD, N);
  gather_kernel<1,false><<<cdiv(N, 4), B, 0, stream>>>(row_start, srcs, escp, selfesc, sS, sD, xh, b2, nullptr, N,
                                                       W3, as3, ad3, xh3, ss3, sd3);

  // ---- layer 3: 8 -> 4x1, mean heads (inputs precomputed) ----
  gather_kernel<2,false><<<cdiv(N, 4), B, 0, stream>>>(row_start, srcs, escp, selfesc, ss3, sd3, xh3, b3, (float*)d_out, N,
                                                       nullptr, nullptr, nullptr, nullptr, nullptr, nullptr);
}

// Round 13
// 385.785 us; speedup vs baseline: 1.3574x; 1.1240x over previous
//
#include <hip/hip_runtime.h>
#include <hip/hip_fp16.h>
#include <cmath>

static inline int cdiv(long a, int b){ return (int)((a + b - 1) / b); }

__device__ __forceinline__ float lrelu(float x){ return x > 0.f ? x : 0.2f * x; }
__device__ __forceinline__ float elu1(float x){ return x > 0.f ? x : expm1f(x); }
__device__ __forceinline__ float fexp(float x){ return __expf(x); }   // native v_exp path
__device__ __forceinline__ float sel4(float4 v, int h){
  float ab = (h & 1) ? v.y : v.x;
  float cd = (h & 1) ? v.w : v.z;
  return (h & 2) ? cd : ab;
}

// compiler-level fence: keep LDS writes (phase1) before LDS reads (phase2)
// within the same wave; HW DS pipe is in-order per wave.
#define WAVE_FENCE() do { asm volatile("" ::: "memory"); __builtin_amdgcn_sched_barrier(0); } while(0)

#define W_SHIFT 7                 // 128 nodes per bucket
#define BUCKET_N (1 << W_SHIFT)
#define NBMAX   1024              // >= number of buckets (782)
#define NCHUNKS 1024              // chunks; also col_scan thread count
#define CH_MAX  3136              // max edges per chunk (E/NCHUNKS = 3125 for E=3.2M)
#define MS_THREADS 1024

// staged record: {src, dst(full), esc01(fp16x2), esc23(fp16x2)}

// ---------------- CSR build (atomic-free scheduling) ----------------

__global__ __launch_bounds__(MS_THREADS)
void hist_chunks_kernel(const int* __restrict__ ei, int E, int CH, int* __restrict__ hist2d){
  __shared__ int s_b[NBMAX];
  int t = threadIdx.x, chunk = blockIdx.x;
  s_b[t] = 0;
  __syncthreads();
  int lo = chunk * CH, hi = min(lo + CH, E);
  for (int e = lo + t; e < hi; e += MS_THREADS)
    atomicAdd(&s_b[ei[E + e] >> W_SHIFT], 1);
  __syncthreads();
  hist2d[(size_t)chunk * NBMAX + t] = s_b[t];
}

// per bucket: exclusive prefix over chunks (in place), total -> bcnt
__global__ __launch_bounds__(NCHUNKS)
void col_scan_kernel(int* __restrict__ hist2d, int* __restrict__ bcnt){
  __shared__ int s[NCHUNKS];
  int b = blockIdx.x, t = threadIdx.x;
  int v = hist2d[(size_t)t * NBMAX + b];
  s[t] = v; __syncthreads();
  #pragma unroll
  for (int off = 1; off < NCHUNKS; off <<= 1){
    int u = (t >= off) ? s[t - off] : 0;
    __syncthreads();
    s[t] += u;
    __syncthreads();
  }
  hist2d[(size_t)t * NBMAX + b] = s[t] - v;
  if (t == NCHUNKS - 1) bcnt[b] = s[t];
}

__global__ void scan_buckets_kernel(const int* __restrict__ bcnt, int nb, int total,
                                    int* __restrict__ bstart, int* __restrict__ row_start, int n){
  __shared__ int s[1024];
  int t = threadIdx.x;
  int v = (t < nb) ? bcnt[t] : 0;
  s[t] = v; __syncthreads();
  #pragma unroll
  for (int off = 1; off < 1024; off <<= 1){
    int u = (t >= off) ? s[t - off] : 0;
    __syncthreads();
    s[t] += u;
    __syncthreads();
  }
  bstart[t] = (t < nb) ? s[t] - v : total;
  if (t == 0){ bstart[NBMAX] = total; row_start[n] = total; }
}

// wev[d*4+h] = sum_c We1[d, h*8+c] * a_e1[h,c]
__global__ void wevec_kernel(const float* __restrict__ We, const float* __restrict__ ae,
                             float* __restrict__ wev){
  int i = threadIdx.x;
  if (i >= 32) return;
  int d = i >> 2, h = i & 3;
  float acc = 0.f;
  #pragma unroll
  for (int c = 0; c < 8; ++c) acc = fmaf(We[d * 32 + h * 8 + c], ae[h * 8 + c], acc);
  wev[d * 4 + h] = acc;
}

// multisplit v2: sort the whole chunk by bucket in LDS, then copy out densely.
__global__ __launch_bounds__(MS_THREADS)
void multisplit_kernel(const int* __restrict__ ei, int E, int CH,
                       const float* __restrict__ eattr, const float* __restrict__ wev,
                       const int* __restrict__ bstart, const int* __restrict__ prefix2d,
                       int4* __restrict__ staged){
  __shared__ int4 s_rec[CH_MAX];        // 50.2 KB
  __shared__ int s_fill[NBMAX];
  __shared__ int s_lbase[NBMAX];
  __shared__ int s_shift[NBMAX];
  __shared__ float s_wev[32];
  int t = threadIdx.x, chunk = blockIdx.x;
  if (t < 32) s_wev[t] = wev[t];
  s_fill[t] = 0;                        // MS_THREADS == NBMAX
  __syncthreads();
  int lo = chunk * CH, hi = min(lo + CH, E);
  int cnt = hi - lo;
  for (int e = lo + t; e < hi; e += MS_THREADS)
    atomicAdd(&s_fill[ei[E + e] >> W_SHIFT], 1);
  __syncthreads();
  int v = s_fill[t];
  s_lbase[t] = v; __syncthreads();
  #pragma unroll
  for (int off = 1; off < NBMAX; off <<= 1){
    int u = (t >= off) ? s_lbase[t - off] : 0;
    __syncthreads();
    s_lbase[t] += u;
    __syncthreads();
  }
  int excl = s_lbase[t] - v;
  s_lbase[t] = excl;
  s_shift[t] = bstart[t] + prefix2d[(size_t)chunk * NBMAX + t] - excl;
  s_fill[t] = 0;
  __syncthreads();
  for (int e = lo + t; e < hi; e += MS_THREADS){
    int d = ei[E + e];
    int b = d >> W_SHIFT;
    const float4* ea = (const float4*)(eattr + (size_t)e * 8);
    float4 v0 = ea[0], v1 = ea[1];
    float av[8] = {v0.x, v0.y, v0.z, v0.w, v1.x, v1.y, v1.z, v1.w};
    float e0 = 0, e1 = 0, e2 = 0, e3 = 0;
    #pragma unroll
    for (int k = 0; k < 8; ++k){
      e0 = fmaf(av[k], s_wev[k * 4 + 0], e0);
      e1 = fmaf(av[k], s_wev[k * 4 + 1], e1);
      e2 = fmaf(av[k], s_wev[k * 4 + 2], e2);
      e3 = fmaf(av[k], s_wev[k * 4 + 3], e3);
    }
    __half2 h01 = __floats2half2_rn(e0, e1);
    __half2 h23 = __floats2half2_rn(e2, e3);
    int pos = s_lbase[b] + atomicAdd(&s_fill[b], 1);
    s_rec[pos] = make_int4(ei[e], d,
                           __builtin_bit_cast(int, h01), __builtin_bit_cast(int, h23));
  }
  __syncthreads();
  for (int i = t; i < cnt; i += MS_THREADS){
    int4 r = s_rec[i];
    staged[s_shift[r.y >> W_SHIFT] + i] = r;
  }
}

// per-bucket: counts -> row_start; permute staged to final CSR (srcs 4B + escp 8B);
// then 8-lane-per-node esc row sums from the L2-hot escp window -> selfesc.
__global__ __launch_bounds__(MS_THREADS)
void bucket_scatter_kernel(const int* __restrict__ bstart, const int4* __restrict__ staged,
                           int n, int* __restrict__ row_start, int* __restrict__ srcs,
                           uint2* __restrict__ escp, float4* __restrict__ selfesc){
  __shared__ int s_cnt[BUCKET_N];
  __shared__ int s_cur[BUCKET_N];
  __shared__ int s_start[BUCKET_N];
  int b = blockIdx.x, t = threadIdx.x;
  int node0 = b << W_SHIFT;
  if (t < BUCKET_N) s_cnt[t] = 0;
  __syncthreads();
  int lo = bstart[b], hi = bstart[b + 1];
  for (int i = lo + t; i < hi; i += MS_THREADS)
    atomicAdd(&s_cnt[staged[i].y & (BUCKET_N - 1)], 1);
  __syncthreads();
  if (t < BUCKET_N) s_cur[t] = s_cnt[t];
  __syncthreads();
  #pragma unroll
  for (int off = 1; off < BUCKET_N; off <<= 1){
    int v = (t < BUCKET_N && t >= off) ? s_cur[t - off] : 0;
    __syncthreads();
    if (t < BUCKET_N) s_cur[t] += v;
    __syncthreads();
  }
  if (t < BUCKET_N){
    int excl = s_cur[t] - s_cnt[t];
    int nd = node0 + t;
    if (nd <= n) row_start[nd] = lo + excl;
    s_start[t] = lo + excl;
    s_cur[t] = lo + excl;
  }
  __syncthreads();
  for (int i = lo + t; i < hi; i += MS_THREADS){
    int4 r = staged[i];
    int pos = atomicAdd(&s_cur[r.y & (BUCKET_N - 1)], 1);
    srcs[pos] = r.x;
    escp[pos] = make_uint2((unsigned)r.z, (unsigned)r.w);
  }
  __syncthreads();
  int nl = t >> 3, sub = t & 7;
  int nd2 = node0 + nl;
  if (nd2 >= n) return;
  int r0 = s_start[nl], r1 = s_start[nl] + s_cnt[nl];
  float e0 = 0, e1 = 0, e2 = 0, e3 = 0;
  for (int k = r0 + sub; k < r1; k += 8){
    uint2 u = escp[k];
    float2 f01 = __half22float2(__builtin_bit_cast(__half2, u.x));
    float2 f23 = __half22float2(__builtin_bit_cast(__half2, u.y));
    e0 += f01.x; e1 += f01.y; e2 += f23.x; e3 += f23.y;
  }
  #pragma unroll
  for (int off = 1; off < 8; off <<= 1){
    e0 += __shfl_xor(e0, off, 64); e1 += __shfl_xor(e1, off, 64);
    e2 += __shfl_xor(e2, off, 64); e3 += __shfl_xor(e3, off, 64);
  }
  if (sub == 0){
    float inv = 1.f / fmaxf((float)s_cnt[nl], 1.f);
    selfesc[nd2] = make_float4(e0 * inv, e1 * inv, e2 * inv, e3 * inv);
  }
}

// ---------------- register-tiled node transform + attention pre-scores ----------------
// Block: 256 threads, 128 rows. Thread (rg,q) computes rows 4rg..4rg+3 x cols 4q..4q+3.
// A staged transposed in LDS (K-halves of <=64); W staged [k][col]. Score epilogue fused.
template<int K>
__global__ __launch_bounds__(256)
void gemm_score_tiled(const float* __restrict__ A, const float* __restrict__ W,
                      const float* __restrict__ asrc, const float* __restrict__ adst,
                      float* __restrict__ out, float* __restrict__ sS,
                      float* __restrict__ sD, int n){
  constexpr int KH = (K > 64) ? 64 : K;
  constexpr int K4 = KH / 4;
  __shared__ float s_AT[KH * 128];
  __shared__ float s_W[K * 32];
  __shared__ float s_as[32], s_ad[32];
  int t = threadIdx.x;
  for (int i = t; i < K * 32; i += 256) s_W[i] = W[i];
  if (t < 32){ s_as[t] = asrc[t]; s_ad[t] = adst[t]; }
  int n0 = blockIdx.x * 128;
  int nrows = min(128, n - n0);
  int rg = t >> 3, q = t & 7;
  float4 acc[4] = {{0,0,0,0},{0,0,0,0},{0,0,0,0},{0,0,0,0}};

  for (int k0 = 0; k0 < K; k0 += KH){
    __syncthreads();
    // stage A[n0+row][k0..k0+KH) transposed: consecutive threads -> consecutive rows
    #pragma unroll
    for (int it = 0; it < 128 * K4 / 256; ++it){
      int idx = t + it * 256;
      int row = idx & 127, k4 = idx >> 7;
      if (row < nrows){
        float4 v = *(const float4*)(A + (size_t)(n0 + row) * K + k0 + 4 * k4);
        s_AT[(4 * k4 + 0) * 128 + row] = v.x;
        s_AT[(4 * k4 + 1) * 128 + row] = v.y;
        s_AT[(4 * k4 + 2) * 128 + row] = v.z;
        s_AT[(4 * k4 + 3) * 128 + row] = v.w;
      }
    }
    __syncthreads();
    #pragma unroll 4
    for (int k = 0; k < KH; ++k){
      float4 a4 = *(const float4*)(s_AT + k * 128 + 4 * rg);
      float4 w4 = *(const float4*)(s_W + (k0 + k) * 32 + 4 * q);
      acc[0].x = fmaf(a4.x, w4.x, acc[0].x); acc[0].y = fmaf(a4.x, w4.y, acc[0].y);
      acc[0].z = fmaf(a4.x, w4.z, acc[0].z); acc[0].w = fmaf(a4.x, w4.w, acc[0].w);
      acc[1].x = fmaf(a4.y, w4.x, acc[1].x); acc[1].y = fmaf(a4.y, w4.y, acc[1].y);
      acc[1].z = fmaf(a4.y, w4.z, acc[1].z); acc[1].w = fmaf(a4.y, w4.w, acc[1].w);
      acc[2].x = fmaf(a4.z, w4.x, acc[2].x); acc[2].y = fmaf(a4.z, w4.y, acc[2].y);
      acc[2].z = fmaf(a4.z, w4.z, acc[2].z); acc[2].w = fmaf(a4.z, w4.w, acc[2].w);
      acc[3].x = fmaf(a4.w, w4.x, acc[3].x); acc[3].y = fmaf(a4.w, w4.y, acc[3].y);
      acc[3].z = fmaf(a4.w, w4.z, acc[3].z); acc[3].w = fmaf(a4.w, w4.w, acc[3].w);
    }
  }

  // stores + fused score epilogue
  float as0 = s_as[4 * q + 0], as1 = s_as[4 * q + 1], as2 = s_as[4 * q + 2], as3 = s_as[4 * q + 3];
  float ad0 = s_ad[4 * q + 0], ad1 = s_ad[4 * q + 1], ad2 = s_ad[4 * q + 2], ad3 = s_ad[4 * q + 3];
  #pragma unroll
  for (int i = 0; i < 4; ++i){
    int row = n0 + 4 * rg + i;
    bool ok = (4 * rg + i) < nrows;
    if (ok) ((float4*)out)[(size_t)row * 8 + q] = acc[i];
    float ps = acc[i].x * as0 + acc[i].y * as1 + acc[i].z * as2 + acc[i].w * as3;
    float pd = acc[i].x * ad0 + acc[i].y * ad1 + acc[i].z * ad2 + acc[i].w * ad3;
    ps += __shfl_xor(ps, 1, 64);
    pd += __shfl_xor(pd, 1, 64);
    if (ok && !(q & 1)){
      sS[(size_t)row * 4 + (q >> 1)] = ps;
      sD[(size_t)row * 4 + (q >> 1)] = pd;
    }
  }
}

// ---------------- CSR gather-aggregate ----------------
// MODE 0: concat heads + bias + ELU (layer1, OUT=32), EDGE: escp fp16x4 + selfesc
// MODE 1: mean heads + bias + ELU + FUSED layer-3 prep (xh3/sS3/sD3); no h2 store
// MODE 2: mean heads + bias         (layer3, OUT=4) — lane-per-edge path
template<int MODE, bool EDGE>
__global__ void gather_kernel(const int* __restrict__ row_start, const int* __restrict__ srcs,
                              const uint2* __restrict__ escp, const float4* __restrict__ selfesc,
                              const float* __restrict__ sS, const float* __restrict__ sD,
                              const float* __restrict__ xh, const float* __restrict__ bias,
                              float* __restrict__ out, int n,
                              const float* __restrict__ W3p, const float* __restrict__ as3p,
                              const float* __restrict__ ad3p, float* __restrict__ xh3,
                              float* __restrict__ ss3, float* __restrict__ sd3){
  int wv = threadIdx.x >> 6, lane = threadIdx.x & 63;
  int node = blockIdx.x * 4 + wv;

  if constexpr (MODE == 2){
    if (node >= n) return;
    int rs = row_start[node], deg = row_start[node + 1] - rs;
    float4 sd4 = ((const float4*)sD)[node];
    float4 acc = {0,0,0,0}, dsum = {0,0,0,0};
    for (int k = lane; k < deg; k += 64){
      int s = srcs[rs + k];
      float4 ss = ((const float4*)sS)[s];
      float4 w;
      w.x = fexp(lrelu(ss.x + sd4.x)); w.y = fexp(lrelu(ss.y + sd4.y));
      w.z = fexp(lrelu(ss.z + sd4.z)); w.w = fexp(lrelu(ss.w + sd4.w));
      dsum.x += w.x; dsum.y += w.y; dsum.z += w.z; dsum.w += w.w;
      float4 xv = ((const float4*)xh)[s];
      acc.x = fmaf(w.x, xv.x, acc.x); acc.y = fmaf(w.y, xv.y, acc.y);
      acc.z = fmaf(w.z, xv.z, acc.z); acc.w = fmaf(w.w, xv.w, acc.w);
    }
    #pragma unroll
    for (int off = 1; off < 64; off <<= 1){
      acc.x += __shfl_xor(acc.x, off, 64); acc.y += __shfl_xor(acc.y, off, 64);
      acc.z += __shfl_xor(acc.z, off, 64); acc.w += __shfl_xor(acc.w, off, 64);
      dsum.x += __shfl_xor(dsum.x, off, 64); dsum.y += __shfl_xor(dsum.y, off, 64);
      dsum.z += __shfl_xor(dsum.z, off, 64); dsum.w += __shfl_xor(dsum.w, off, 64);
    }
    if (lane == 0){
      float4 ssn = ((const float4*)sS)[node];
      float4 wsf;
      wsf.x = fexp(lrelu(ssn.x + sd4.x)); wsf.y = fexp(lrelu(ssn.y + sd4.y));
      wsf.z = fexp(lrelu(ssn.z + sd4.z)); wsf.w = fexp(lrelu(ssn.w + sd4.w));
      float4 xvn = ((const float4*)xh)[node];
      float v = (acc.x + wsf.x * xvn.x) / (dsum.x + wsf.x + 1e-16f)
              + (acc.y + wsf.y * xvn.y) / (dsum.y + wsf.y + 1e-16f)
              + (acc.z + wsf.z * xvn.z) / (dsum.z + wsf.z + 1e-16f)
              + (acc.w + wsf.w * xvn.w) / (dsum.w + wsf.w + 1e-16f);
      out[node] = 0.25f * v + bias[0];
    }
    return;
  } else {
  __shared__ float4 s_w[4][64];
  __shared__ int    s_src[4][64];
  __shared__ float  s_w3[32];
  __shared__ float  s_a3[8];
  if constexpr (MODE == 1){
    if (threadIdx.x < 32) s_w3[threadIdx.x] = W3p[threadIdx.x];
    if (threadIdx.x < 8)
      s_a3[threadIdx.x] = (threadIdx.x < 4) ? as3p[threadIdx.x] : ad3p[threadIdx.x - 4];
    __syncthreads();
  }
  if (node >= n) return;
  int rs = row_start[node], deg = row_start[node + 1] - rs;
  float4 sd4 = ((const float4*)sD)[node];
  int q = lane & 7;
  int h = q >> 1;
  int sg = lane >> 3;
  float4 acc = {0,0,0,0};
  float dacc = 0.f;

  for (int base = 0; base < deg; base += 64){
    int k = base + lane;
    float4 w = {0,0,0,0}; int s = 0;
    if (k < deg){
      s = srcs[rs + k];
      float4 ss = ((const float4*)sS)[s];
      float a0 = ss.x + sd4.x, a1 = ss.y + sd4.y, a2 = ss.z + sd4.z, a3 = ss.w + sd4.w;
      if constexpr (EDGE){
        uint2 u = escp[rs + k];
        float2 f01 = __half22float2(__builtin_bit_cast(__half2, u.x));
        float2 f23 = __half22float2(__builtin_bit_cast(__half2, u.y));
        a0 += f01.x; a1 += f01.y; a2 += f23.x; a3 += f23.y;
      }
      w.x = fexp(lrelu(a0)); w.y = fexp(lrelu(a1));
      w.z = fexp(lrelu(a2)); w.w = fexp(lrelu(a3));
    }
    s_w[wv][lane] = w;
    s_src[wv][lane] = s;
    WAVE_FENCE();
    int nvalid = min(deg - base, 64);
    const float* s_wf = (const float*)&s_w[wv][0];
    #pragma unroll
    for (int i = 0; i < 8; ++i){
      int slot = i * 8 + sg;
      if (slot < nvalid){
        int s2 = s_src[wv][slot];
        float wg = s_wf[slot * 4 + h];
        float4 xv = ((const float4*)xh)[(size_t)s2 * 8 + q];
        dacc += wg;
        acc.x = fmaf(wg, xv.x, acc.x); acc.y = fmaf(wg, xv.y, acc.y);
        acc.z = fmaf(wg, xv.z, acc.z); acc.w = fmaf(wg, xv.w, acc.w);
      }
    }
    WAVE_FENCE();
  }

  #pragma unroll
  for (int off = 8; off < 64; off <<= 1){
    acc.x += __shfl_xor(acc.x, off, 64); acc.y += __shfl_xor(acc.y, off, 64);
    acc.z += __shfl_xor(acc.z, off, 64); acc.w += __shfl_xor(acc.w, off, 64);
    dacc  += __shfl_xor(dacc,  off, 64);
  }
  float4 ssn = ((const float4*)sS)[node];
  float a_self = sel4(ssn, h) + sel4(sd4, h);
  if constexpr (EDGE) a_self += sel4(selfesc[node], h);
  float wsel = fexp(lrelu(a_self));
  float4 xvn = ((const float4*)xh)[(size_t)node * 8 + q];
  acc.x = fmaf(wsel, xvn.x, acc.x); acc.y = fmaf(wsel, xvn.y, acc.y);
  acc.z = fmaf(wsel, xvn.z, acc.z); acc.w = fmaf(wsel, xvn.w, acc.w);
  dacc += wsel;
  float rin = 1.f / (dacc + 1e-16f);
  float4 val = {acc.x * rin, acc.y * rin, acc.z * rin, acc.w * rin};

  if constexpr (MODE == 0){
    float4 b4 = ((const float4*)bias)[q];
    val.x = elu1(val.x + b4.x); val.y = elu1(val.y + b4.y);
    val.z = elu1(val.z + b4.z); val.w = elu1(val.w + b4.w);
    if (lane < 8) ((float4*)out)[(size_t)node * 8 + lane] = val;
  } else {
    val.x += __shfl_xor(val.x, 2, 64); val.y += __shfl_xor(val.y, 2, 64);
    val.z += __shfl_xor(val.z, 2, 64); val.w += __shfl_xor(val.w, 2, 64);
    val.x += __shfl_xor(val.x, 4, 64); val.y += __shfl_xor(val.y, 4, 64);
    val.z += __shfl_xor(val.z, 4, 64); val.w += __shfl_xor(val.w, 4, 64);
    float4 b4 = ((const float4*)bias)[q & 1];
    val.x = elu1(val.x * 0.25f + b4.x); val.y = elu1(val.y * 0.25f + b4.y);
    val.z = elu1(val.z * 0.25f + b4.z); val.w = elu1(val.w * 0.25f + b4.w);
    float4 oth;
    oth.x = __shfl_xor(val.x, 1, 64); oth.y = __shfl_xor(val.y, 1, 64);
    oth.z = __shfl_xor(val.z, 1, 64); oth.w = __shfl_xor(val.w, 1, 64);
    float h2v[8];
    if (q & 1){
      h2v[0] = oth.x; h2v[1] = oth.y; h2v[2] = oth.z; h2v[3] = oth.w;
      h2v[4] = val.x; h2v[5] = val.y; h2v[6] = val.z; h2v[7] = val.w;
    } else {
      h2v[0] = val.x; h2v[1] = val.y; h2v[2] = val.z; h2v[3] = val.w;
      h2v[4] = oth.x; h2v[5] = oth.y; h2v[6] = oth.z; h2v[7] = oth.w;
    }
    float x3[4];
    #pragma unroll
    for (int j = 0; j < 4; ++j){
      float a = 0.f;
      #pragma unroll
      for (int k = 0; k < 8; ++k) a = fmaf(h2v[k], s_w3[k * 4 + j], a);
      x3[j] = a;
    }
    if (lane == 0){
      ((float4*)xh3)[node] = make_float4(x3[0], x3[1], x3[2], x3[3]);
      ((float4*)ss3)[node] = make_float4(x3[0] * s_a3[0], x3[1] * s_a3[1],
                                         x3[2] * s_a3[2], x3[3] * s_a3[3]);
      ((float4*)sd3)[node] = make_float4(x3[0] * s_a3[4], x3[1] * s_a3[5],
                                         x3[2] * s_a3[6], x3[3] * s_a3[7]);
    }
  }
  }
}

// ---------------- launcher ----------------

extern "C" void kernel_launch(void* const* d_in, const int* in_sizes, int n_in,
                              void* d_out, int out_size, void* d_ws, size_t ws_size,
                              hipStream_t stream){
  const float* x     = (const float*)d_in[0];
  const float* eattr = (const float*)d_in[1];
  const int*   ei    = (const int*)d_in[2];
  const float* W1  = (const float*)d_in[3];
  const float* as1 = (const float*)d_in[4];
  const float* ad1 = (const float*)d_in[5];
  const float* We1 = (const float*)d_in[6];
  const float* ae1 = (const float*)d_in[7];
  const float* b1  = (const float*)d_in[8];
  const float* W2  = (const float*)d_in[9];
  const float* as2 = (const float*)d_in[10];
  const float* ad2 = (const float*)d_in[11];
  const float* b2  = (const float*)d_in[12];
  const float* W3  = (const float*)d_in[13];
  const float* as3 = (const float*)d_in[14];
  const float* ad3 = (const float*)d_in[15];
  const float* b3  = (const float*)d_in[16];

  const int N = in_sizes[0] / 128;
  const int E = in_sizes[2] / 2;
  const int nb_buckets = (N + BUCKET_N - 1) >> W_SHIFT;   // 782 for N=100000
  const int CH = cdiv(E, NCHUNKS);                        // 3125 (<= CH_MAX)

  char* b0 = (char*)d_ws;
  int4* staged = (int4*)b0;
  float* fp = (float*)b0;
  float* xh = fp; fp += (size_t)N * 32;
  float* sS = fp; fp += (size_t)N * 4;
  float* sD = fp; fp += (size_t)N * 4;
  float* h1 = fp; fp += (size_t)N * 32;
  int*  srcs = (int*)(b0 + (size_t)E * 16);
  uint2* escp = (uint2*)(b0 + (size_t)E * 20);
  int* hist2d = (int*)(b0 + (size_t)E * 28);
  float4* selfesc = (float4*)(hist2d + (size_t)NCHUNKS * NBMAX);
  float* xh3 = (float*)(selfesc + N);
  float* ss3 = xh3 + (size_t)N * 4;
  float* sd3 = ss3 + (size_t)N * 4;
  int* ip = (int*)(sd3 + (size_t)N * 4);
  int* bcnt      = ip; ip += NBMAX;
  int* bstart    = ip; ip += NBMAX + 1;
  int* row_start = ip; ip += N + 1;
  float* wev = (float*)ip;

  const int B = 256;

  // ---- CSR build: plan (no global atomics) -> LDS-sorted multisplit -> bucket scatter ----
  wevec_kernel<<<1, 32, 0, stream>>>(We1, ae1, wev);
  hist_chunks_kernel<<<NCHUNKS, MS_THREADS, 0, stream>>>(ei, E, CH, hist2d);
  col_scan_kernel<<<nb_buckets, NCHUNKS, 0, stream>>>(hist2d, bcnt);
  scan_buckets_kernel<<<1, 1024, 0, stream>>>(bcnt, nb_buckets, E, bstart, row_start, N);
  multisplit_kernel<<<NCHUNKS, MS_THREADS, 0, stream>>>(ei, E, CH, eattr, wev, bstart, hist2d, staged);
  bucket_scatter_kernel<<<nb_buckets, MS_THREADS, 0, stream>>>(bstart, staged, N, row_start, srcs, escp, selfesc);

  // ---- layer 1: 128 -> 4x8, concat, edge scores ----
  gemm_score_tiled<128><<<cdiv(N, 128), B, 0, stream>>>(x, W1, as1, ad1, xh, sS, sD, N);
  gather_kernel<0,true><<<cdiv(N, 4), B, 0, stream>>>(row_start, srcs, escp, selfesc, sS, sD, xh, b1, h1, N,
                                                      nullptr, nullptr, nullptr, nullptr, nullptr, nullptr);

  // ---- layer 2: 32 -> 4x8, mean heads; fused layer-3 prep ----
  gemm_score_tiled<32><<<cdiv(N, 128), B, 0, stream>>>(h1, W2, as2, ad2, xh, sS, sD, N);
  gather_kernel<1,false><<<cdiv(N, 4), B, 0, stream>>>(row_start, srcs, escp, selfesc, sS, sD, xh, b2, nullptr, N,
                                                       W3, as3, ad3, xh3, ss3, sd3);

  // ---- layer 3: 8 -> 4x1, mean heads (inputs precomputed) ----
  gather_kernel<2,false><<<cdiv(N, 4), B, 0, stream>>>(row_start, srcs, escp, selfesc, ss3, sd3, xh3, b3, (float*)d_out, N,
                                                       nullptr, nullptr, nullptr, nullptr, nullptr, nullptr);
}

// Round 14
// 379.109 us; speedup vs baseline: 1.3813x; 1.0176x over previous
//
#include <hip/hip_runtime.h>
#include <hip/hip_fp16.h>
#include <cmath>

static inline int cdiv(long a, int b){ return (int)((a + b - 1) / b); }

__device__ __forceinline__ float lrelu(float x){ return fmaxf(x, 0.2f * x); }
__device__ __forceinline__ float elu1(float x){ return x > 0.f ? x : expm1f(x); }
__device__ __forceinline__ float fexp2(float x){ return exp2f(x); }   // v_exp_f32
__device__ __forceinline__ float sel4(float4 v, int h){
  float ab = (h & 1) ? v.y : v.x;
  float cd = (h & 1) ? v.w : v.z;
  return (h & 2) ? cd : ab;
}

#define W_SHIFT 7                 // 128 nodes per bucket
#define BUCKET_N (1 << W_SHIFT)
#define NBMAX   1024              // >= number of buckets (782)
#define NCHUNKS 1024              // chunks; also col_scan thread count
#define CH_MAX  3136              // max edges per chunk (E/NCHUNKS = 3125)
#define MS_THREADS 1024

// staged record: {src, dst(full), esc01(fp16x2), esc23(fp16x2)}; esc pre-scaled by log2e

// ---------------- CSR build (atomic-free scheduling) ----------------

__global__ __launch_bounds__(MS_THREADS)
void hist_chunks_kernel(const int* __restrict__ ei, int E, int CH, int* __restrict__ hist2d){
  __shared__ int s_b[NBMAX];
  int t = threadIdx.x, chunk = blockIdx.x;
  s_b[t] = 0;
  __syncthreads();
  int lo = chunk * CH, hi = min(lo + CH, E);
  for (int e = lo + t; e < hi; e += MS_THREADS)
    atomicAdd(&s_b[ei[E + e] >> W_SHIFT], 1);
  __syncthreads();
  hist2d[(size_t)chunk * NBMAX + t] = s_b[t];
}

__global__ __launch_bounds__(NCHUNKS)
void col_scan_kernel(int* __restrict__ hist2d, int* __restrict__ bcnt){
  __shared__ int s[NCHUNKS];
  int b = blockIdx.x, t = threadIdx.x;
  int v = hist2d[(size_t)t * NBMAX + b];
  s[t] = v; __syncthreads();
  #pragma unroll
  for (int off = 1; off < NCHUNKS; off <<= 1){
    int u = (t >= off) ? s[t - off] : 0;
    __syncthreads();
    s[t] += u;
    __syncthreads();
  }
  hist2d[(size_t)t * NBMAX + b] = s[t] - v;
  if (t == NCHUNKS - 1) bcnt[b] = s[t];
}

__global__ void scan_buckets_kernel(const int* __restrict__ bcnt, int nb, int total,
                                    int* __restrict__ bstart, int* __restrict__ row_start, int n){
  __shared__ int s[1024];
  int t = threadIdx.x;
  int v = (t < nb) ? bcnt[t] : 0;
  s[t] = v; __syncthreads();
  #pragma unroll
  for (int off = 1; off < 1024; off <<= 1){
    int u = (t >= off) ? s[t - off] : 0;
    __syncthreads();
    s[t] += u;
    __syncthreads();
  }
  bstart[t] = (t < nb) ? s[t] - v : total;
  if (t == 0){ bstart[NBMAX] = total; row_start[n] = total; }
}

// wev[d*4+h] = log2e * sum_c We1[d,h*8+c]*a_e1[h,c]; avecs = scaled attention vecs:
// [as1s 0..31 | ad1s 32..63 | as2s 64..95 | ad2s 96..127 | as3s 128..131 | ad3s 132..135]
__global__ void prep_kernel(const float* __restrict__ We, const float* __restrict__ ae,
                            const float* __restrict__ as1, const float* __restrict__ ad1,
                            const float* __restrict__ as2, const float* __restrict__ ad2,
                            const float* __restrict__ as3, const float* __restrict__ ad3,
                            float* __restrict__ wev, float* __restrict__ avecs){
  const float L2E = 1.4426950408889634f;
  int i = threadIdx.x;
  if (i < 32){
    int d = i >> 2, h = i & 3;
    float acc = 0.f;
    #pragma unroll
    for (int c = 0; c < 8; ++c) acc = fmaf(We[d * 32 + h * 8 + c], ae[h * 8 + c], acc);
    wev[d * 4 + h] = acc * L2E;
    avecs[i]      = as1[i] * L2E;
    avecs[32 + i] = ad1[i] * L2E;
    avecs[64 + i] = as2[i] * L2E;
    avecs[96 + i] = ad2[i] * L2E;
  }
  if (i < 4){
    avecs[128 + i] = as3[i] * L2E;
    avecs[132 + i] = ad3[i] * L2E;
  }
}

// multisplit v2: sort the whole chunk by bucket in LDS, then copy out densely.
__global__ __launch_bounds__(MS_THREADS)
void multisplit_kernel(const int* __restrict__ ei, int E, int CH,
                       const float* __restrict__ eattr, const float* __restrict__ wev,
                       const int* __restrict__ bstart, const int* __restrict__ prefix2d,
                       int4* __restrict__ staged){
  __shared__ int4 s_rec[CH_MAX];        // 50.2 KB
  __shared__ int s_fill[NBMAX];
  __shared__ int s_lbase[NBMAX];
  __shared__ int s_shift[NBMAX];
  __shared__ float s_wev[32];
  int t = threadIdx.x, chunk = blockIdx.x;
  if (t < 32) s_wev[t] = wev[t];
  s_fill[t] = 0;
  __syncthreads();
  int lo = chunk * CH, hi = min(lo + CH, E);
  int cnt = hi - lo;
  for (int e = lo + t; e < hi; e += MS_THREADS)
    atomicAdd(&s_fill[ei[E + e] >> W_SHIFT], 1);
  __syncthreads();
  int v = s_fill[t];
  s_lbase[t] = v; __syncthreads();
  #pragma unroll
  for (int off = 1; off < NBMAX; off <<= 1){
    int u = (t >= off) ? s_lbase[t - off] : 0;
    __syncthreads();
    s_lbase[t] += u;
    __syncthreads();
  }
  int excl = s_lbase[t] - v;
  s_lbase[t] = excl;
  s_shift[t] = bstart[t] + prefix2d[(size_t)chunk * NBMAX + t] - excl;
  s_fill[t] = 0;
  __syncthreads();
  for (int e = lo + t; e < hi; e += MS_THREADS){
    int d = ei[E + e];
    int b = d >> W_SHIFT;
    const float4* ea = (const float4*)(eattr + (size_t)e * 8);
    float4 v0 = ea[0], v1 = ea[1];
    float av[8] = {v0.x, v0.y, v0.z, v0.w, v1.x, v1.y, v1.z, v1.w};
    float e0 = 0, e1 = 0, e2 = 0, e3 = 0;
    #pragma unroll
    for (int k = 0; k < 8; ++k){
      e0 = fmaf(av[k], s_wev[k * 4 + 0], e0);
      e1 = fmaf(av[k], s_wev[k * 4 + 1], e1);
      e2 = fmaf(av[k], s_wev[k * 4 + 2], e2);
      e3 = fmaf(av[k], s_wev[k * 4 + 3], e3);
    }
    __half2 h01 = __floats2half2_rn(e0, e1);
    __half2 h23 = __floats2half2_rn(e2, e3);
    int pos = s_lbase[b] + atomicAdd(&s_fill[b], 1);
    s_rec[pos] = make_int4(ei[e], d,
                           __builtin_bit_cast(int, h01), __builtin_bit_cast(int, h23));
  }
  __syncthreads();
  for (int i = t; i < cnt; i += MS_THREADS){
    int4 r = s_rec[i];
    staged[s_shift[r.y >> W_SHIFT] + i] = r;
  }
}

// per-bucket: counts -> row_start; permute staged to final CSR (srcs 4B + escp 8B);
// then 8-lane-per-node esc row sums from the L2-hot escp window -> selfesc.
__global__ __launch_bounds__(MS_THREADS)
void bucket_scatter_kernel(const int* __restrict__ bstart, const int4* __restrict__ staged,
                           int n, int* __restrict__ row_start, int* __restrict__ srcs,
                           uint2* __restrict__ escp, float4* __restrict__ selfesc){
  __shared__ int s_cnt[BUCKET_N];
  __shared__ int s_cur[BUCKET_N];
  __shared__ int s_start[BUCKET_N];
  int b = blockIdx.x, t = threadIdx.x;
  int node0 = b << W_SHIFT;
  if (t < BUCKET_N) s_cnt[t] = 0;
  __syncthreads();
  int lo = bstart[b], hi = bstart[b + 1];
  for (int i = lo + t; i < hi; i += MS_THREADS)
    atomicAdd(&s_cnt[staged[i].y & (BUCKET_N - 1)], 1);
  __syncthreads();
  if (t < BUCKET_N) s_cur[t] = s_cnt[t];
  __syncthreads();
  #pragma unroll
  for (int off = 1; off < BUCKET_N; off <<= 1){
    int v = (t < BUCKET_N && t >= off) ? s_cur[t - off] : 0;
    __syncthreads();
    if (t < BUCKET_N) s_cur[t] += v;
    __syncthreads();
  }
  if (t < BUCKET_N){
    int excl = s_cur[t] - s_cnt[t];
    int nd = node0 + t;
    if (nd <= n) row_start[nd] = lo + excl;
    s_start[t] = lo + excl;
    s_cur[t] = lo + excl;
  }
  __syncthreads();
  for (int i = lo + t; i < hi; i += MS_THREADS){
    int4 r = staged[i];
    int pos = atomicAdd(&s_cur[r.y & (BUCKET_N - 1)], 1);
    srcs[pos] = r.x;
    escp[pos] = make_uint2((unsigned)r.z, (unsigned)r.w);
  }
  __syncthreads();
  int nl = t >> 3, sub = t & 7;
  int nd2 = node0 + nl;
  if (nd2 >= n) return;
  int r0 = s_start[nl], r1 = s_start[nl] + s_cnt[nl];
  float e0 = 0, e1 = 0, e2 = 0, e3 = 0;
  for (int k = r0 + sub; k < r1; k += 8){
    uint2 u = escp[k];
    float2 f01 = __half22float2(__builtin_bit_cast(__half2, u.x));
    float2 f23 = __half22float2(__builtin_bit_cast(__half2, u.y));
    e0 += f01.x; e1 += f01.y; e2 += f23.x; e3 += f23.y;
  }
  #pragma unroll
  for (int off = 1; off < 8; off <<= 1){
    e0 += __shfl_xor(e0, off, 64); e1 += __shfl_xor(e1, off, 64);
    e2 += __shfl_xor(e2, off, 64); e3 += __shfl_xor(e3, off, 64);
  }
  if (sub == 0){
    float inv = 1.f / fmaxf((float)s_cnt[nl], 1.f);
    selfesc[nd2] = make_float4(e0 * inv, e1 * inv, e2 * inv, e3 * inv);
  }
}

// ---------------- register-tiled node transform (pure GEMM) ----------------
template<int K>
__global__ __launch_bounds__(256)
void gemm_tiled(const float* __restrict__ A, const float* __restrict__ W,
                float* __restrict__ out, int n){
  constexpr int KH = (K > 64) ? 64 : K;
  constexpr int K4 = KH / 4;
  __shared__ float s_AT[KH * 128];
  __shared__ float s_W[K * 32];
  int t = threadIdx.x;
  for (int i = t; i < K * 32; i += 256) s_W[i] = W[i];
  int n0 = blockIdx.x * 128;
  int nrows = min(128, n - n0);
  int rg = t >> 3, q = t & 7;
  float4 acc[4] = {{0,0,0,0},{0,0,0,0},{0,0,0,0},{0,0,0,0}};

  for (int k0 = 0; k0 < K; k0 += KH){
    __syncthreads();
    #pragma unroll
    for (int it = 0; it < 128 * K4 / 256; ++it){
      int idx = t + it * 256;
      int row = idx & 127, k4 = idx >> 7;
      if (row < nrows){
        float4 v = *(const float4*)(A + (size_t)(n0 + row) * K + k0 + 4 * k4);
        s_AT[(4 * k4 + 0) * 128 + row] = v.x;
        s_AT[(4 * k4 + 1) * 128 + row] = v.y;
        s_AT[(4 * k4 + 2) * 128 + row] = v.z;
        s_AT[(4 * k4 + 3) * 128 + row] = v.w;
      }
    }
    __syncthreads();
    #pragma unroll 4
    for (int k = 0; k < KH; ++k){
      float4 a4 = *(const float4*)(s_AT + k * 128 + 4 * rg);
      float4 w4 = *(const float4*)(s_W + (k0 + k) * 32 + 4 * q);
      acc[0].x = fmaf(a4.x, w4.x, acc[0].x); acc[0].y = fmaf(a4.x, w4.y, acc[0].y);
      acc[0].z = fmaf(a4.x, w4.z, acc[0].z); acc[0].w = fmaf(a4.x, w4.w, acc[0].w);
      acc[1].x = fmaf(a4.y, w4.x, acc[1].x); acc[1].y = fmaf(a4.y, w4.y, acc[1].y);
      acc[1].z = fmaf(a4.y, w4.z, acc[1].z); acc[1].w = fmaf(a4.y, w4.w, acc[1].w);
      acc[2].x = fmaf(a4.z, w4.x, acc[2].x); acc[2].y = fmaf(a4.z, w4.y, acc[2].y);
      acc[2].z = fmaf(a4.z, w4.z, acc[2].z); acc[2].w = fmaf(a4.z, w4.w, acc[2].w);
      acc[3].x = fmaf(a4.w, w4.x, acc[3].x); acc[3].y = fmaf(a4.w, w4.y, acc[3].y);
      acc[3].z = fmaf(a4.w, w4.z, acc[3].z); acc[3].w = fmaf(a4.w, w4.w, acc[3].w);
    }
  }
  #pragma unroll
  for (int i = 0; i < 4; ++i){
    int row = n0 + 4 * rg + i;
    if ((4 * rg + i) < nrows) ((float4*)out)[(size_t)row * 8 + q] = acc[i];
  }
}

// ---------------- one-phase LDS-free CSR gather-aggregate ----------------
// Scores recomputed in-register from the gathered row (pre-scaled by log2e).
// MODE 0: concat heads + bias + ELU (layer1), EDGE: escp fp16x4 + selfesc
// MODE 1: mean heads + bias + ELU + fused layer-3 transform -> xh3
// MODE 2: mean heads + bias (layer3); xh = xh3 table (float4/node)
template<int MODE, bool EDGE>
__global__ void gather_kernel(const int* __restrict__ row_start, const int* __restrict__ srcs,
                              const uint2* __restrict__ escp, const float4* __restrict__ selfesc,
                              const float* __restrict__ xh, const float* __restrict__ avq,
                              const float* __restrict__ bias, float* __restrict__ out, int n,
                              const float* __restrict__ W3p, float* __restrict__ xh3){
  int wv = threadIdx.x >> 6, lane = threadIdx.x & 63;
  int node = blockIdx.x * 4 + wv;

  if constexpr (MODE == 2){
    if (node >= n) return;
    int rs = row_start[node], deg = row_start[node + 1] - rs;
    float4 a3s = *(const float4*)avq;
    float4 a3d = *(const float4*)(avq + 4);
    float4 xvn = ((const float4*)xh)[node];
    float4 sdn = {xvn.x * a3d.x, xvn.y * a3d.y, xvn.z * a3d.z, xvn.w * a3d.w};
    float4 acc = {0,0,0,0}, dsum = {0,0,0,0};
    for (int k = lane; k < deg; k += 64){
      int s = srcs[rs + k];
      float4 xv = ((const float4*)xh)[s];
      float4 w;
      w.x = fexp2(lrelu(fmaf(xv.x, a3s.x, sdn.x)));
      w.y = fexp2(lrelu(fmaf(xv.y, a3s.y, sdn.y)));
      w.z = fexp2(lrelu(fmaf(xv.z, a3s.z, sdn.z)));
      w.w = fexp2(lrelu(fmaf(xv.w, a3s.w, sdn.w)));
      dsum.x += w.x; dsum.y += w.y; dsum.z += w.z; dsum.w += w.w;
      acc.x = fmaf(w.x, xv.x, acc.x); acc.y = fmaf(w.y, xv.y, acc.y);
      acc.z = fmaf(w.z, xv.z, acc.z); acc.w = fmaf(w.w, xv.w, acc.w);
    }
    #pragma unroll
    for (int off = 1; off < 64; off <<= 1){
      acc.x += __shfl_xor(acc.x, off, 64); acc.y += __shfl_xor(acc.y, off, 64);
      acc.z += __shfl_xor(acc.z, off, 64); acc.w += __shfl_xor(acc.w, off, 64);
      dsum.x += __shfl_xor(dsum.x, off, 64); dsum.y += __shfl_xor(dsum.y, off, 64);
      dsum.z += __shfl_xor(dsum.z, off, 64); dsum.w += __shfl_xor(dsum.w, off, 64);
    }
    if (lane == 0){
      float4 wsf;
      wsf.x = fexp2(lrelu(fmaf(xvn.x, a3s.x, sdn.x)));
      wsf.y = fexp2(lrelu(fmaf(xvn.y, a3s.y, sdn.y)));
      wsf.z = fexp2(lrelu(fmaf(xvn.z, a3s.z, sdn.z)));
      wsf.w = fexp2(lrelu(fmaf(xvn.w, a3s.w, sdn.w)));
      float v = (acc.x + wsf.x * xvn.x) / (dsum.x + wsf.x + 1e-16f)
              + (acc.y + wsf.y * xvn.y) / (dsum.y + wsf.y + 1e-16f)
              + (acc.z + wsf.z * xvn.z) / (dsum.z + wsf.z + 1e-16f)
              + (acc.w + wsf.w * xvn.w) / (dsum.w + wsf.w + 1e-16f);
      out[node] = 0.25f * v + bias[0];
    }
    return;
  } else {
  __shared__ float s_w3[32];
  if constexpr (MODE == 1){
    if (threadIdx.x < 32) s_w3[threadIdx.x] = W3p[threadIdx.x];
    __syncthreads();
  }
  if (node >= n) return;
  int rs = row_start[node], deg = row_start[node + 1] - rs;
  int q = lane & 7, sg = lane >> 3, h = q >> 1;
  float4 as4 = ((const float4*)avq)[q];
  float4 ad4 = ((const float4*)(avq + 32))[q];
  float4 xvn = ((const float4*)xh)[(size_t)node * 8 + q];
  float pd = xvn.x * ad4.x;
  pd = fmaf(xvn.y, ad4.y, pd); pd = fmaf(xvn.z, ad4.z, pd); pd = fmaf(xvn.w, ad4.w, pd);
  float sdh = pd + __shfl_xor(pd, 1, 64);
  float4 acc = {0,0,0,0};
  float dacc = 0.f;
  const int* sp = srcs + rs;

  for (int base = 0; base < deg; base += 8){
    int k = base + sg;
    if (k < deg){
      int s = sp[k];
      float4 xv = ((const float4*)xh)[(size_t)s * 8 + q];
      float p = xv.x * as4.x;
      p = fmaf(xv.y, as4.y, p); p = fmaf(xv.z, as4.z, p); p = fmaf(xv.w, as4.w, p);
      float a = p + __shfl_xor(p, 1, 64) + sdh;
      if constexpr (EDGE){
        uint2 u = escp[rs + k];
        float2 f01 = __half22float2(__builtin_bit_cast(__half2, u.x));
        float2 f23 = __half22float2(__builtin_bit_cast(__half2, u.y));
        a += (h == 0) ? f01.x : (h == 1) ? f01.y : (h == 2) ? f23.x : f23.y;
      }
      float w = fexp2(lrelu(a));
      dacc += w;
      acc.x = fmaf(w, xv.x, acc.x); acc.y = fmaf(w, xv.y, acc.y);
      acc.z = fmaf(w, xv.z, acc.z); acc.w = fmaf(w, xv.w, acc.w);
    }
  }

  #pragma unroll
  for (int off = 8; off < 64; off <<= 1){
    acc.x += __shfl_xor(acc.x, off, 64); acc.y += __shfl_xor(acc.y, off, 64);
    acc.z += __shfl_xor(acc.z, off, 64); acc.w += __shfl_xor(acc.w, off, 64);
    dacc  += __shfl_xor(dacc,  off, 64);
  }
  // self-loop
  float p0 = xvn.x * as4.x;
  p0 = fmaf(xvn.y, as4.y, p0); p0 = fmaf(xvn.z, as4.z, p0); p0 = fmaf(xvn.w, as4.w, p0);
  float a_self = p0 + __shfl_xor(p0, 1, 64) + sdh;
  if constexpr (EDGE) a_self += sel4(selfesc[node], h);
  float wsel = fexp2(lrelu(a_self));
  acc.x = fmaf(wsel, xvn.x, acc.x); acc.y = fmaf(wsel, xvn.y, acc.y);
  acc.z = fmaf(wsel, xvn.z, acc.z); acc.w = fmaf(wsel, xvn.w, acc.w);
  dacc += wsel;
  float rin = 1.f / (dacc + 1e-16f);
  float4 val = {acc.x * rin, acc.y * rin, acc.z * rin, acc.w * rin};

  if constexpr (MODE == 0){
    float4 b4 = ((const float4*)bias)[q];
    val.x = elu1(val.x + b4.x); val.y = elu1(val.y + b4.y);
    val.z = elu1(val.z + b4.z); val.w = elu1(val.w + b4.w);
    if (lane < 8) ((float4*)out)[(size_t)node * 8 + lane] = val;
  } else {
    val.x += __shfl_xor(val.x, 2, 64); val.y += __shfl_xor(val.y, 2, 64);
    val.z += __shfl_xor(val.z, 2, 64); val.w += __shfl_xor(val.w, 2, 64);
    val.x += __shfl_xor(val.x, 4, 64); val.y += __shfl_xor(val.y, 4, 64);
    val.z += __shfl_xor(val.z, 4, 64); val.w += __shfl_xor(val.w, 4, 64);
    float4 b4 = ((const float4*)bias)[q & 1];
    val.x = elu1(val.x * 0.25f + b4.x); val.y = elu1(val.y * 0.25f + b4.y);
    val.z = elu1(val.z * 0.25f + b4.z); val.w = elu1(val.w * 0.25f + b4.w);
    float4 oth;
    oth.x = __shfl_xor(val.x, 1, 64); oth.y = __shfl_xor(val.y, 1, 64);
    oth.z = __shfl_xor(val.z, 1, 64); oth.w = __shfl_xor(val.w, 1, 64);
    float h2v[8];
    if (q & 1){
      h2v[0] = oth.x; h2v[1] = oth.y; h2v[2] = oth.z; h2v[3] = oth.w;
      h2v[4] = val.x; h2v[5] = val.y; h2v[6] = val.z; h2v[7] = val.w;
    } else {
      h2v[0] = val.x; h2v[1] = val.y; h2v[2] = val.z; h2v[3] = val.w;
      h2v[4] = oth.x; h2v[5] = oth.y; h2v[6] = oth.z; h2v[7] = oth.w;
    }
    float x3[4];
    #pragma unroll
    for (int j = 0; j < 4; ++j){
      float a = 0.f;
      #pragma unroll
      for (int k = 0; k < 8; ++k) a = fmaf(h2v[k], s_w3[k * 4 + j], a);
      x3[j] = a;
    }
    if (lane == 0)
      ((float4*)xh3)[node] = make_float4(x3[0], x3[1], x3[2], x3[3]);
  }
  }
}

// ---------------- launcher ----------------

extern "C" void kernel_launch(void* const* d_in, const int* in_sizes, int n_in,
                              void* d_out, int out_size, void* d_ws, size_t ws_size,
                              hipStream_t stream){
  const float* x     = (const float*)d_in[0];
  const float* eattr = (const float*)d_in[1];
  const int*   ei    = (const int*)d_in[2];
  const float* W1  = (const float*)d_in[3];
  const float* as1 = (const float*)d_in[4];
  const float* ad1 = (const float*)d_in[5];
  const float* We1 = (const float*)d_in[6];
  const float* ae1 = (const float*)d_in[7];
  const float* b1  = (const float*)d_in[8];
  const float* W2  = (const float*)d_in[9];
  const float* as2 = (const float*)d_in[10];
  const float* ad2 = (const float*)d_in[11];
  const float* b2  = (const float*)d_in[12];
  const float* W3  = (const float*)d_in[13];
  const float* as3 = (const float*)d_in[14];
  const float* ad3 = (const float*)d_in[15];
  const float* b3  = (const float*)d_in[16];

  const int N = in_sizes[0] / 128;
  const int E = in_sizes[2] / 2;
  const int nb_buckets = (N + BUCKET_N - 1) >> W_SHIFT;   // 782 for N=100000
  const int CH = cdiv(E, NCHUNKS);                        // 3125 (<= CH_MAX)

  char* b0 = (char*)d_ws;
  int4* staged = (int4*)b0;                 // E*16; aliased by xh/h1 after CSR build
  float* fp = (float*)b0;
  float* xh = fp; fp += (size_t)N * 32;
  float* h1 = fp; fp += (size_t)N * 32;
  int*  srcs = (int*)(b0 + (size_t)E * 16);
  uint2* escp = (uint2*)(b0 + (size_t)E * 20);
  int* hist2d = (int*)(b0 + (size_t)E * 28);
  float4* selfesc = (float4*)(hist2d + (size_t)NCHUNKS * NBMAX);
  float* xh3 = (float*)(selfesc + N);
  int* ip = (int*)(xh3 + (size_t)N * 4);
  int* bcnt      = ip; ip += NBMAX;
  int* bstart    = ip; ip += NBMAX + 1;
  int* row_start = ip; ip += N + 1;
  float* wev   = (float*)ip;
  float* avecs = wev + 32;

  const int B = 256;

  // ---- CSR build: plan (no global atomics) -> LDS-sorted multisplit -> bucket scatter ----
  prep_kernel<<<1, 64, 0, stream>>>(We1, ae1, as1, ad1, as2, ad2, as3, ad3, wev, avecs);
  hist_chunks_kernel<<<NCHUNKS, MS_THREADS, 0, stream>>>(ei, E, CH, hist2d);
  col_scan_kernel<<<nb_buckets, NCHUNKS, 0, stream>>>(hist2d, bcnt);
  scan_buckets_kernel<<<1, 1024, 0, stream>>>(bcnt, nb_buckets, E, bstart, row_start, N);
  multisplit_kernel<<<NCHUNKS, MS_THREADS, 0, stream>>>(ei, E, CH, eattr, wev, bstart, hist2d, staged);
  bucket_scatter_kernel<<<nb_buckets, MS_THREADS, 0, stream>>>(bstart, staged, N, row_start, srcs, escp, selfesc);

  // ---- layer 1: 128 -> 4x8, concat, edge scores ----
  gemm_tiled<128><<<cdiv(N, 128), B, 0, stream>>>(x, W1, xh, N);
  gather_kernel<0,true><<<cdiv(N, 4), B, 0, stream>>>(row_start, srcs, escp, selfesc, xh, avecs,
                                                      b1, h1, N, nullptr, nullptr);

  // ---- layer 2: 32 -> 4x8, mean heads; fused layer-3 transform ----
  gemm_tiled<32><<<cdiv(N, 128), B, 0, stream>>>(h1, W2, xh, N);
  gather_kernel<1,false><<<cdiv(N, 4), B, 0, stream>>>(row_start, srcs, escp, selfesc, xh, avecs + 64,
                                                       b2, nullptr, N, W3, xh3);

  // ---- layer 3: 8 -> 4x1, mean heads (xh3 table, scores componentwise) ----
  gather_kernel<2,false><<<cdiv(N, 4), B, 0, stream>>>(row_start, srcs, escp, selfesc, xh3, avecs + 128,
                                                       b3, (float*)d_out, N, nullptr, nullptr);
}

// Round 15
// 378.009 us; speedup vs baseline: 1.3853x; 1.0029x over previous
//
#include <hip/hip_runtime.h>
#include <hip/hip_fp16.h>
#include <cmath>

static inline int cdiv(long a, int b){ return (int)((a + b - 1) / b); }

__device__ __forceinline__ float lrelu(float x){ return fmaxf(x, 0.2f * x); }
__device__ __forceinline__ float elu1(float x){ return x > 0.f ? x : expm1f(x); }
__device__ __forceinline__ float fexp2(float x){ return exp2f(x); }   // v_exp_f32
__device__ __forceinline__ float sel4(float4 v, int h){
  float ab = (h & 1) ? v.y : v.x;
  float cd = (h & 1) ? v.w : v.z;
  return (h & 2) ? cd : ab;
}
__device__ __forceinline__ float dot8(float4 a, float4 b, float4 u, float4 v){
  float p = a.x * u.x;
  p = fmaf(a.y, u.y, p); p = fmaf(a.z, u.z, p); p = fmaf(a.w, u.w, p);
  p = fmaf(b.x, v.x, p); p = fmaf(b.y, v.y, p); p = fmaf(b.z, v.z, p);
  return fmaf(b.w, v.w, p);
}

#define W_SHIFT 7                 // 128 nodes per bucket
#define BUCKET_N (1 << W_SHIFT)
#define NBMAX   1024              // >= number of buckets (782)
#define NCHUNKS 1024              // chunks; also col_scan thread count
#define CH_MAX  3136              // max edges per chunk (E/NCHUNKS = 3125)
#define MS_THREADS 1024

// staged record: {src, dst(full), esc01(fp16x2), esc23(fp16x2)}; esc pre-scaled by log2e

// ---------------- CSR build (atomic-free scheduling) ----------------

__global__ __launch_bounds__(MS_THREADS)
void hist_chunks_kernel(const int* __restrict__ ei, int E, int CH, int* __restrict__ hist2d){
  __shared__ int s_b[NBMAX];
  int t = threadIdx.x, chunk = blockIdx.x;
  s_b[t] = 0;
  __syncthreads();
  int lo = chunk * CH, hi = min(lo + CH, E);
  for (int e = lo + t; e < hi; e += MS_THREADS)
    atomicAdd(&s_b[ei[E + e] >> W_SHIFT], 1);
  __syncthreads();
  hist2d[(size_t)chunk * NBMAX + t] = s_b[t];
}

__global__ __launch_bounds__(NCHUNKS)
void col_scan_kernel(int* __restrict__ hist2d, int* __restrict__ bcnt){
  __shared__ int s[NCHUNKS];
  int b = blockIdx.x, t = threadIdx.x;
  int v = hist2d[(size_t)t * NBMAX + b];
  s[t] = v; __syncthreads();
  #pragma unroll
  for (int off = 1; off < NCHUNKS; off <<= 1){
    int u = (t >= off) ? s[t - off] : 0;
    __syncthreads();
    s[t] += u;
    __syncthreads();
  }
  hist2d[(size_t)t * NBMAX + b] = s[t] - v;
  if (t == NCHUNKS - 1) bcnt[b] = s[t];
}

__global__ void scan_buckets_kernel(const int* __restrict__ bcnt, int nb, int total,
                                    int* __restrict__ bstart, int* __restrict__ row_start, int n){
  __shared__ int s[1024];
  int t = threadIdx.x;
  int v = (t < nb) ? bcnt[t] : 0;
  s[t] = v; __syncthreads();
  #pragma unroll
  for (int off = 1; off < 1024; off <<= 1){
    int u = (t >= off) ? s[t - off] : 0;
    __syncthreads();
    s[t] += u;
    __syncthreads();
  }
  bstart[t] = (t < nb) ? s[t] - v : total;
  if (t == 0){ bstart[NBMAX] = total; row_start[n] = total; }
}

// wev scaled by log2e; avecs = scaled attention vecs:
// [as1s 0..31 | ad1s 32..63 | as2s 64..95 | ad2s 96..127 | as3s 128..131 | ad3s 132..135]
__global__ void prep_kernel(const float* __restrict__ We, const float* __restrict__ ae,
                            const float* __restrict__ as1, const float* __restrict__ ad1,
                            const float* __restrict__ as2, const float* __restrict__ ad2,
                            const float* __restrict__ as3, const float* __restrict__ ad3,
                            float* __restrict__ wev, float* __restrict__ avecs){
  const float L2E = 1.4426950408889634f;
  int i = threadIdx.x;
  if (i < 32){
    int d = i >> 2, h = i & 3;
    float acc = 0.f;
    #pragma unroll
    for (int c = 0; c < 8; ++c) acc = fmaf(We[d * 32 + h * 8 + c], ae[h * 8 + c], acc);
    wev[d * 4 + h] = acc * L2E;
    avecs[i]      = as1[i] * L2E;
    avecs[32 + i] = ad1[i] * L2E;
    avecs[64 + i] = as2[i] * L2E;
    avecs[96 + i] = ad2[i] * L2E;
  }
  if (i < 4){
    avecs[128 + i] = as3[i] * L2E;
    avecs[132 + i] = ad3[i] * L2E;
  }
}

// multisplit v2: sort the whole chunk by bucket in LDS, then copy out densely.
__global__ __launch_bounds__(MS_THREADS)
void multisplit_kernel(const int* __restrict__ ei, int E, int CH,
                       const float* __restrict__ eattr, const float* __restrict__ wev,
                       const int* __restrict__ bstart, const int* __restrict__ prefix2d,
                       int4* __restrict__ staged){
  __shared__ int4 s_rec[CH_MAX];        // 50.2 KB
  __shared__ int s_fill[NBMAX];
  __shared__ int s_lbase[NBMAX];
  __shared__ int s_shift[NBMAX];
  __shared__ float s_wev[32];
  int t = threadIdx.x, chunk = blockIdx.x;
  if (t < 32) s_wev[t] = wev[t];
  s_fill[t] = 0;
  __syncthreads();
  int lo = chunk * CH, hi = min(lo + CH, E);
  int cnt = hi - lo;
  for (int e = lo + t; e < hi; e += MS_THREADS)
    atomicAdd(&s_fill[ei[E + e] >> W_SHIFT], 1);
  __syncthreads();
  int v = s_fill[t];
  s_lbase[t] = v; __syncthreads();
  #pragma unroll
  for (int off = 1; off < NBMAX; off <<= 1){
    int u = (t >= off) ? s_lbase[t - off] : 0;
    __syncthreads();
    s_lbase[t] += u;
    __syncthreads();
  }
  int excl = s_lbase[t] - v;
  s_lbase[t] = excl;
  s_shift[t] = bstart[t] + prefix2d[(size_t)chunk * NBMAX + t] - excl;
  s_fill[t] = 0;
  __syncthreads();
  for (int e = lo + t; e < hi; e += MS_THREADS){
    int d = ei[E + e];
    int b = d >> W_SHIFT;
    const float4* ea = (const float4*)(eattr + (size_t)e * 8);
    float4 v0 = ea[0], v1 = ea[1];
    float av[8] = {v0.x, v0.y, v0.z, v0.w, v1.x, v1.y, v1.z, v1.w};
    float e0 = 0, e1 = 0, e2 = 0, e3 = 0;
    #pragma unroll
    for (int k = 0; k < 8; ++k){
      e0 = fmaf(av[k], s_wev[k * 4 + 0], e0);
      e1 = fmaf(av[k], s_wev[k * 4 + 1], e1);
      e2 = fmaf(av[k], s_wev[k * 4 + 2], e2);
      e3 = fmaf(av[k], s_wev[k * 4 + 3], e3);
    }
    __half2 h01 = __floats2half2_rn(e0, e1);
    __half2 h23 = __floats2half2_rn(e2, e3);
    int pos = s_lbase[b] + atomicAdd(&s_fill[b], 1);
    s_rec[pos] = make_int4(ei[e], d,
                           __builtin_bit_cast(int, h01), __builtin_bit_cast(int, h23));
  }
  __syncthreads();
  for (int i = t; i < cnt; i += MS_THREADS){
    int4 r = s_rec[i];
    staged[s_shift[r.y >> W_SHIFT] + i] = r;
  }
}

// per-bucket: counts -> row_start; permute staged to final CSR (srcs 4B + escp 8B);
// then 8-lane-per-node esc row sums from the L2-hot escp window -> selfesc.
__global__ __launch_bounds__(MS_THREADS)
void bucket_scatter_kernel(const int* __restrict__ bstart, const int4* __restrict__ staged,
                           int n, int* __restrict__ row_start, int* __restrict__ srcs,
                           uint2* __restrict__ escp, float4* __restrict__ selfesc){
  __shared__ int s_cnt[BUCKET_N];
  __shared__ int s_cur[BUCKET_N];
  __shared__ int s_start[BUCKET_N];
  int b = blockIdx.x, t = threadIdx.x;
  int node0 = b << W_SHIFT;
  if (t < BUCKET_N) s_cnt[t] = 0;
  __syncthreads();
  int lo = bstart[b], hi = bstart[b + 1];
  for (int i = lo + t; i < hi; i += MS_THREADS)
    atomicAdd(&s_cnt[staged[i].y & (BUCKET_N - 1)], 1);
  __syncthreads();
  if (t < BUCKET_N) s_cur[t] = s_cnt[t];
  __syncthreads();
  #pragma unroll
  for (int off = 1; off < BUCKET_N; off <<= 1){
    int v = (t < BUCKET_N && t >= off) ? s_cur[t - off] : 0;
    __syncthreads();
    if (t < BUCKET_N) s_cur[t] += v;
    __syncthreads();
  }
  if (t < BUCKET_N){
    int excl = s_cur[t] - s_cnt[t];
    int nd = node0 + t;
    if (nd <= n) row_start[nd] = lo + excl;
    s_start[t] = lo + excl;
    s_cur[t] = lo + excl;
  }
  __syncthreads();
  for (int i = lo + t; i < hi; i += MS_THREADS){
    int4 r = staged[i];
    int pos = atomicAdd(&s_cur[r.y & (BUCKET_N - 1)], 1);
    srcs[pos] = r.x;
    escp[pos] = make_uint2((unsigned)r.z, (unsigned)r.w);
  }
  __syncthreads();
  int nl = t >> 3, sub = t & 7;
  int nd2 = node0 + nl;
  if (nd2 >= n) return;
  int r0 = s_start[nl], r1 = s_start[nl] + s_cnt[nl];
  float e0 = 0, e1 = 0, e2 = 0, e3 = 0;
  for (int k = r0 + sub; k < r1; k += 8){
    uint2 u = escp[k];
    float2 f01 = __half22float2(__builtin_bit_cast(__half2, u.x));
    float2 f23 = __half22float2(__builtin_bit_cast(__half2, u.y));
    e0 += f01.x; e1 += f01.y; e2 += f23.x; e3 += f23.y;
  }
  #pragma unroll
  for (int off = 1; off < 8; off <<= 1){
    e0 += __shfl_xor(e0, off, 64); e1 += __shfl_xor(e1, off, 64);
    e2 += __shfl_xor(e2, off, 64); e3 += __shfl_xor(e3, off, 64);
  }
  if (sub == 0){
    float inv = 1.f / fmaxf((float)s_cnt[nl], 1.f);
    selfesc[nd2] = make_float4(e0 * inv, e1 * inv, e2 * inv, e3 * inv);
  }
}

// ---------------- register-tiled node transform (pure GEMM) ----------------
template<int K>
__global__ __launch_bounds__(256)
void gemm_tiled(const float* __restrict__ A, const float* __restrict__ W,
                float* __restrict__ out, int n){
  constexpr int KH = (K > 64) ? 64 : K;
  constexpr int K4 = KH / 4;
  __shared__ float s_AT[KH * 128];
  __shared__ float s_W[K * 32];
  int t = threadIdx.x;
  for (int i = t; i < K * 32; i += 256) s_W[i] = W[i];
  int n0 = blockIdx.x * 128;
  int nrows = min(128, n - n0);
  int rg = t >> 3, q = t & 7;
  float4 acc[4] = {{0,0,0,0},{0,0,0,0},{0,0,0,0},{0,0,0,0}};

  for (int k0 = 0; k0 < K; k0 += KH){
    __syncthreads();
    #pragma unroll
    for (int it = 0; it < 128 * K4 / 256; ++it){
      int idx = t + it * 256;
      int row = idx & 127, k4 = idx >> 7;
      if (row < nrows){
        float4 v = *(const float4*)(A + (size_t)(n0 + row) * K + k0 + 4 * k4);
        s_AT[(4 * k4 + 0) * 128 + row] = v.x;
        s_AT[(4 * k4 + 1) * 128 + row] = v.y;
        s_AT[(4 * k4 + 2) * 128 + row] = v.z;
        s_AT[(4 * k4 + 3) * 128 + row] = v.w;
      }
    }
    __syncthreads();
    #pragma unroll 4
    for (int k = 0; k < KH; ++k){
      float4 a4 = *(const float4*)(s_AT + k * 128 + 4 * rg);
      float4 w4 = *(const float4*)(s_W + (k0 + k) * 32 + 4 * q);
      acc[0].x = fmaf(a4.x, w4.x, acc[0].x); acc[0].y = fmaf(a4.x, w4.y, acc[0].y);
      acc[0].z = fmaf(a4.x, w4.z, acc[0].z); acc[0].w = fmaf(a4.x, w4.w, acc[0].w);
      acc[1].x = fmaf(a4.y, w4.x, acc[1].x); acc[1].y = fmaf(a4.y, w4.y, acc[1].y);
      acc[1].z = fmaf(a4.y, w4.z, acc[1].z); acc[1].w = fmaf(a4.y, w4.w, acc[1].w);
      acc[2].x = fmaf(a4.z, w4.x, acc[2].x); acc[2].y = fmaf(a4.z, w4.y, acc[2].y);
      acc[2].z = fmaf(a4.z, w4.z, acc[2].z); acc[2].w = fmaf(a4.z, w4.w, acc[2].w);
      acc[3].x = fmaf(a4.w, w4.x, acc[3].x); acc[3].y = fmaf(a4.w, w4.y, acc[3].y);
      acc[3].z = fmaf(a4.w, w4.z, acc[3].z); acc[3].w = fmaf(a4.w, w4.w, acc[3].w);
    }
  }
  #pragma unroll
  for (int i = 0; i < 4; ++i){
    int row = n0 + 4 * rg + i;
    if ((4 * rg + i) < nrows) ((float4*)out)[(size_t)row * 8 + q] = acc[i];
  }
}

// ---------------- one-phase CSR gather: 4 lanes/edge, no score shfl ----------------
// lane = (sg 0..15, h 0..3): 16 edges in flight; head h's full 8 elements in-lane.
// MODE 0: concat heads + bias + ELU (layer1), EDGE: escp fp16x4 + selfesc
// MODE 1: mean heads + bias + ELU + fused layer-3 transform -> xh3
// MODE 2: mean heads + bias (layer3); xh = xh3 table (float4/node)
template<int MODE, bool EDGE>
__global__ void gather_kernel(const int* __restrict__ row_start, const int* __restrict__ srcs,
                              const uint2* __restrict__ escp, const float4* __restrict__ selfesc,
                              const float* __restrict__ xh, const float* __restrict__ avq,
                              const float* __restrict__ bias, float* __restrict__ out, int n,
                              const float* __restrict__ W3p, float* __restrict__ xh3){
  int wv = threadIdx.x >> 6, lane = threadIdx.x & 63;
  int node = blockIdx.x * 4 + wv;

  if constexpr (MODE == 2){
    if (node >= n) return;
    int rs = row_start[node], deg = row_start[node + 1] - rs;
    float4 a3s = *(const float4*)avq;
    float4 a3d = *(const float4*)(avq + 4);
    float4 xvn = ((const float4*)xh)[node];
    float4 sdn = {xvn.x * a3d.x, xvn.y * a3d.y, xvn.z * a3d.z, xvn.w * a3d.w};
    float4 acc = {0,0,0,0}, dsum = {0,0,0,0};
    for (int k = lane; k < deg; k += 64){
      int s = srcs[rs + k];
      float4 xv = ((const float4*)xh)[s];
      float4 w;
      w.x = fexp2(lrelu(fmaf(xv.x, a3s.x, sdn.x)));
      w.y = fexp2(lrelu(fmaf(xv.y, a3s.y, sdn.y)));
      w.z = fexp2(lrelu(fmaf(xv.z, a3s.z, sdn.z)));
      w.w = fexp2(lrelu(fmaf(xv.w, a3s.w, sdn.w)));
      dsum.x += w.x; dsum.y += w.y; dsum.z += w.z; dsum.w += w.w;
      acc.x = fmaf(w.x, xv.x, acc.x); acc.y = fmaf(w.y, xv.y, acc.y);
      acc.z = fmaf(w.z, xv.z, acc.z); acc.w = fmaf(w.w, xv.w, acc.w);
    }
    #pragma unroll
    for (int off = 1; off < 64; off <<= 1){
      acc.x += __shfl_xor(acc.x, off, 64); acc.y += __shfl_xor(acc.y, off, 64);
      acc.z += __shfl_xor(acc.z, off, 64); acc.w += __shfl_xor(acc.w, off, 64);
      dsum.x += __shfl_xor(dsum.x, off, 64); dsum.y += __shfl_xor(dsum.y, off, 64);
      dsum.z += __shfl_xor(dsum.z, off, 64); dsum.w += __shfl_xor(dsum.w, off, 64);
    }
    if (lane == 0){
      float4 wsf;
      wsf.x = fexp2(lrelu(fmaf(xvn.x, a3s.x, sdn.x)));
      wsf.y = fexp2(lrelu(fmaf(xvn.y, a3s.y, sdn.y)));
      wsf.z = fexp2(lrelu(fmaf(xvn.z, a3s.z, sdn.z)));
      wsf.w = fexp2(lrelu(fmaf(xvn.w, a3s.w, sdn.w)));
      float v = (acc.x + wsf.x * xvn.x) / (dsum.x + wsf.x + 1e-16f)
              + (acc.y + wsf.y * xvn.y) / (dsum.y + wsf.y + 1e-16f)
              + (acc.z + wsf.z * xvn.z) / (dsum.z + wsf.z + 1e-16f)
              + (acc.w + wsf.w * xvn.w) / (dsum.w + wsf.w + 1e-16f);
      out[node] = 0.25f * v + bias[0];
    }
    return;
  } else {
  __shared__ float s_w3[32];
  if constexpr (MODE == 1){
    if (threadIdx.x < 32) s_w3[threadIdx.x] = W3p[threadIdx.x];
    __syncthreads();
  }
  if (node >= n) return;
  int rs = row_start[node], deg = row_start[node + 1] - rs;
  int h = lane & 3, sg = lane >> 2;          // head, edge slot (16 edges/iter)
  const float4* xh4 = (const float4*)xh;
  float4 as0 = ((const float4*)avq)[2 * h];
  float4 as1v = ((const float4*)avq)[2 * h + 1];
  float4 ad0 = ((const float4*)(avq + 32))[2 * h];
  float4 ad1v = ((const float4*)(avq + 32))[2 * h + 1];
  float4 xn0 = xh4[(size_t)node * 8 + 2 * h];
  float4 xn1 = xh4[(size_t)node * 8 + 2 * h + 1];
  float sdh = dot8(xn0, xn1, ad0, ad1v);     // dst score, fully in-lane
  float4 acc0 = {0,0,0,0}, acc1 = {0,0,0,0};
  float dacc = 0.f;
  const int* sp = srcs + rs;

  for (int base = 0; base < deg; base += 16){
    int k = base + sg;
    if (k < deg){
      int s = sp[k];
      float4 xv0 = xh4[(size_t)s * 8 + 2 * h];
      float4 xv1 = xh4[(size_t)s * 8 + 2 * h + 1];
      float a = dot8(xv0, xv1, as0, as1v) + sdh;
      if constexpr (EDGE){
        uint2 u = escp[rs + k];
        float2 f01 = __half22float2(__builtin_bit_cast(__half2, u.x));
        float2 f23 = __half22float2(__builtin_bit_cast(__half2, u.y));
        a += (h == 0) ? f01.x : (h == 1) ? f01.y : (h == 2) ? f23.x : f23.y;
      }
      float w = fexp2(lrelu(a));
      dacc += w;
      acc0.x = fmaf(w, xv0.x, acc0.x); acc0.y = fmaf(w, xv0.y, acc0.y);
      acc0.z = fmaf(w, xv0.z, acc0.z); acc0.w = fmaf(w, xv0.w, acc0.w);
      acc1.x = fmaf(w, xv1.x, acc1.x); acc1.y = fmaf(w, xv1.y, acc1.y);
      acc1.z = fmaf(w, xv1.z, acc1.z); acc1.w = fmaf(w, xv1.w, acc1.w);
    }
  }

  // reduce over the 16 edge slots (heads stay separate: xor bits 2..5)
  #pragma unroll
  for (int off = 4; off < 64; off <<= 1){
    acc0.x += __shfl_xor(acc0.x, off, 64); acc0.y += __shfl_xor(acc0.y, off, 64);
    acc0.z += __shfl_xor(acc0.z, off, 64); acc0.w += __shfl_xor(acc0.w, off, 64);
    acc1.x += __shfl_xor(acc1.x, off, 64); acc1.y += __shfl_xor(acc1.y, off, 64);
    acc1.z += __shfl_xor(acc1.z, off, 64); acc1.w += __shfl_xor(acc1.w, off, 64);
    dacc   += __shfl_xor(dacc,   off, 64);
  }
  // self-loop (identical in all sg groups; harmless redundancy)
  float a_self = dot8(xn0, xn1, as0, as1v) + sdh;
  if constexpr (EDGE) a_self += sel4(selfesc[node], h);
  float wsel = fexp2(lrelu(a_self));
  acc0.x = fmaf(wsel, xn0.x, acc0.x); acc0.y = fmaf(wsel, xn0.y, acc0.y);
  acc0.z = fmaf(wsel, xn0.z, acc0.z); acc0.w = fmaf(wsel, xn0.w, acc0.w);
  acc1.x = fmaf(wsel, xn1.x, acc1.x); acc1.y = fmaf(wsel, xn1.y, acc1.y);
  acc1.z = fmaf(wsel, xn1.z, acc1.z); acc1.w = fmaf(wsel, xn1.w, acc1.w);
  dacc += wsel;
  float rin = 1.f / (dacc + 1e-16f);
  float4 v0 = {acc0.x * rin, acc0.y * rin, acc0.z * rin, acc0.w * rin};
  float4 v1 = {acc1.x * rin, acc1.y * rin, acc1.z * rin, acc1.w * rin};

  if constexpr (MODE == 0){
    if (sg == 0){
      float4 ba = ((const float4*)bias)[2 * h];
      float4 bb = ((const float4*)bias)[2 * h + 1];
      v0.x = elu1(v0.x + ba.x); v0.y = elu1(v0.y + ba.y);
      v0.z = elu1(v0.z + ba.z); v0.w = elu1(v0.w + ba.w);
      v1.x = elu1(v1.x + bb.x); v1.y = elu1(v1.y + bb.y);
      v1.z = elu1(v1.z + bb.z); v1.w = elu1(v1.w + bb.w);
      ((float4*)out)[(size_t)node * 8 + 2 * h] = v0;
      ((float4*)out)[(size_t)node * 8 + 2 * h + 1] = v1;
    }
  } else {
    // mean over the 4 heads: butterfly on head bits (xor 1, 2)
    #pragma unroll
    for (int off = 1; off < 4; off <<= 1){
      v0.x += __shfl_xor(v0.x, off, 64); v0.y += __shfl_xor(v0.y, off, 64);
      v0.z += __shfl_xor(v0.z, off, 64); v0.w += __shfl_xor(v0.w, off, 64);
      v1.x += __shfl_xor(v1.x, off, 64); v1.y += __shfl_xor(v1.y, off, 64);
      v1.z += __shfl_xor(v1.z, off, 64); v1.w += __shfl_xor(v1.w, off, 64);
    }
    float4 ba = ((const float4*)bias)[0];
    float4 bb = ((const float4*)bias)[1];
    float h2v[8];
    h2v[0] = elu1(v0.x * 0.25f + ba.x); h2v[1] = elu1(v0.y * 0.25f + ba.y);
    h2v[2] = elu1(v0.z * 0.25f + ba.z); h2v[3] = elu1(v0.w * 0.25f + ba.w);
    h2v[4] = elu1(v1.x * 0.25f + bb.x); h2v[5] = elu1(v1.y * 0.25f + bb.y);
    h2v[6] = elu1(v1.z * 0.25f + bb.z); h2v[7] = elu1(v1.w * 0.25f + bb.w);
    // fused layer-3 transform: lane computes output column h
    if (sg == 0){
      float a = 0.f;
      #pragma unroll
      for (int k = 0; k < 8; ++k) a = fmaf(h2v[k], s_w3[k * 4 + h], a);
      xh3[(size_t)node * 4 + h] = a;
    }
  }
  }
}

// ---------------- launcher ----------------

extern "C" void kernel_launch(void* const* d_in, const int* in_sizes, int n_in,
                              void* d_out, int out_size, void* d_ws, size_t ws_size,
                              hipStream_t stream){
  const float* x     = (const float*)d_in[0];
  const float* eattr = (const float*)d_in[1];
  const int*   ei    = (const int*)d_in[2];
  const float* W1  = (const float*)d_in[3];
  const float* as1 = (const float*)d_in[4];
  const float* ad1 = (const float*)d_in[5];
  const float* We1 = (const float*)d_in[6];
  const float* ae1 = (const float*)d_in[7];
  const float* b1  = (const float*)d_in[8];
  const float* W2  = (const float*)d_in[9];
  const float* as2 = (const float*)d_in[10];
  const float* ad2 = (const float*)d_in[11];
  const float* b2  = (const float*)d_in[12];
  const float* W3  = (const float*)d_in[13];
  const float* as3 = (const float*)d_in[14];
  const float* ad3 = (const float*)d_in[15];
  const float* b3  = (const float*)d_in[16];

  const int N = in_sizes[0] / 128;
  const int E = in_sizes[2] / 2;
  const int nb_buckets = (N + BUCKET_N - 1) >> W_SHIFT;   // 782 for N=100000
  const int CH = cdiv(E, NCHUNKS);                        // 3125 (<= CH_MAX)

  char* b0 = (char*)d_ws;
  int4* staged = (int4*)b0;                 // E*16; aliased by xh/h1 after CSR build
  float* fp = (float*)b0;
  float* xh = fp; fp += (size_t)N * 32;
  float* h1 = fp; fp += (size_t)N * 32;
  int*  srcs = (int*)(b0 + (size_t)E * 16);
  uint2* escp = (uint2*)(b0 + (size_t)E * 20);
  int* hist2d = (int*)(b0 + (size_t)E * 28);
  float4* selfesc = (float4*)(hist2d + (size_t)NCHUNKS * NBMAX);
  float* xh3 = (float*)(selfesc + N);
  int* ip = (int*)(xh3 + (size_t)N * 4);
  int* bcnt      = ip; ip += NBMAX;
  int* bstart    = ip; ip += NBMAX + 1;
  int* row_start = ip; ip += N + 1;
  float* wev   = (float*)ip;
  float* avecs = wev + 32;

  const int B = 256;

  // ---- CSR build: plan (no global atomics) -> LDS-sorted multisplit -> bucket scatter ----
  prep_kernel<<<1, 64, 0, stream>>>(We1, ae1, as1, ad1, as2, ad2, as3, ad3, wev, avecs);
  hist_chunks_kernel<<<NCHUNKS, MS_THREADS, 0, stream>>>(ei, E, CH, hist2d);
  col_scan_kernel<<<nb_buckets, NCHUNKS, 0, stream>>>(hist2d, bcnt);
  scan_buckets_kernel<<<1, 1024, 0, stream>>>(bcnt, nb_buckets, E, bstart, row_start, N);
  multisplit_kernel<<<NCHUNKS, MS_THREADS, 0, stream>>>(ei, E, CH, eattr, wev, bstart, hist2d, staged);
  bucket_scatter_kernel<<<nb_buckets, MS_THREADS, 0, stream>>>(bstart, staged, N, row_start, srcs, escp, selfesc);

  // ---- layer 1: 128 -> 4x8, concat, edge scores ----
  gemm_tiled<128><<<cdiv(N, 128), B, 0, stream>>>(x, W1, xh, N);
  gather_kernel<0,true><<<cdiv(N, 4), B, 0, stream>>>(row_start, srcs, escp, selfesc, xh, avecs,
                                                      b1, h1, N, nullptr, nullptr);

  // ---- layer 2: 32 -> 4x8, mean heads; fused layer-3 transform ----
  gemm_tiled<32><<<cdiv(N, 128), B, 0, stream>>>(h1, W2, xh, N);
  gather_kernel<1,false><<<cdiv(N, 4), B, 0, stream>>>(row_start, srcs, escp, selfesc, xh, avecs + 64,
                                                       b2, nullptr, N, W3, xh3);

  // ---- layer 3: 8 -> 4x1, mean heads (xh3 table, scores componentwise) ----
  gather_kernel<2,false><<<cdiv(N, 4), B, 0, stream>>>(row_start, srcs, escp, selfesc, xh3, avecs + 128,
                                                       b3, (float*)d_out, N, nullptr, nullptr);
}

// Round 16
// 355.063 us; speedup vs baseline: 1.4749x; 1.0646x over previous
//
#include <hip/hip_runtime.h>
#include <hip/hip_fp16.h>
#include <cmath>

static inline int cdiv(long a, int b){ return (int)((a + b - 1) / b); }

__device__ __forceinline__ float lrelu(float x){ return fmaxf(x, 0.2f * x); }
__device__ __forceinline__ float elu1(float x){ return x > 0.f ? x : expm1f(x); }
__device__ __forceinline__ float fexp2(float x){ return exp2f(x); }   // v_exp_f32
__device__ __forceinline__ float sel4(float4 v, int h){
  float ab = (h & 1) ? v.y : v.x;
  float cd = (h & 1) ? v.w : v.z;
  return (h & 2) ? cd : ab;
}
__device__ __forceinline__ float dot8(float4 a, float4 b, float4 u, float4 v){
  float p = a.x * u.x;
  p = fmaf(a.y, u.y, p); p = fmaf(a.z, u.z, p); p = fmaf(a.w, u.w, p);
  p = fmaf(b.x, v.x, p); p = fmaf(b.y, v.y, p); p = fmaf(b.z, v.z, p);
  return fmaf(b.w, v.w, p);
}

// 1024-thread block exclusive scan, 2 barriers (wave shfl + 16 wave totals).
// s_wsum: LDS int[16]. After return, s_wsum[15] == grand total.
__device__ __forceinline__ int block_exscan_1024(int v, int* s_wsum, int t){
  int lane = t & 63, w = t >> 6;
  int x = v;
  #pragma unroll
  for (int off = 1; off < 64; off <<= 1){
    int u = __shfl_up(x, off, 64);
    if (lane >= off) x += u;
  }
  if (lane == 63) s_wsum[w] = x;
  __syncthreads();
  if (w == 0 && lane < 16){
    int y = s_wsum[lane];
    #pragma unroll
    for (int off = 1; off < 16; off <<= 1){
      int u = __shfl_up(y, off, 64);
      if (lane >= off) y += u;
    }
    s_wsum[lane] = y;
  }
  __syncthreads();
  int wbase = w ? s_wsum[w - 1] : 0;
  return wbase + x - v;
}

#define W_SHIFT 7                 // 128 nodes per bucket
#define BUCKET_N (1 << W_SHIFT)
#define NBMAX   1024              // >= number of buckets (782)
#define NCHUNKS 1024              // chunks; also col_scan thread count
#define CH_MAX  3136              // max edges per chunk (E/NCHUNKS = 3125)
#define MS_THREADS 1024

// staged record: {src, dst(full), esc01(fp16x2), esc23(fp16x2)}; esc pre-scaled by log2e

// ---------------- CSR build (atomic-free scheduling) ----------------

__global__ __launch_bounds__(MS_THREADS)
void hist_chunks_kernel(const int* __restrict__ ei, int E, int CH, int* __restrict__ hist2d){
  __shared__ int s_b[NBMAX];
  int t = threadIdx.x, chunk = blockIdx.x;
  s_b[t] = 0;
  __syncthreads();
  int lo = chunk * CH, hi = min(lo + CH, E);
  for (int e = lo + t; e < hi; e += MS_THREADS)
    atomicAdd(&s_b[ei[E + e] >> W_SHIFT], 1);
  __syncthreads();
  hist2d[(size_t)chunk * NBMAX + t] = s_b[t];
}

// per bucket: exclusive prefix over chunks (in place), total -> bcnt
__global__ __launch_bounds__(NCHUNKS)
void col_scan_kernel(int* __restrict__ hist2d, int* __restrict__ bcnt){
  __shared__ int s_wsum[16];
  int b = blockIdx.x, t = threadIdx.x;
  int v = hist2d[(size_t)t * NBMAX + b];
  int excl = block_exscan_1024(v, s_wsum, t);
  hist2d[(size_t)t * NBMAX + b] = excl;
  if (t == 0) bcnt[b] = s_wsum[15];
}

__global__ __launch_bounds__(1024)
void scan_buckets_kernel(const int* __restrict__ bcnt, int nb, int total,
                         int* __restrict__ bstart, int* __restrict__ row_start, int n){
  __shared__ int s_wsum[16];
  int t = threadIdx.x;
  int v = (t < nb) ? bcnt[t] : 0;
  int excl = block_exscan_1024(v, s_wsum, t);
  bstart[t] = excl;                       // for t >= nb, excl == total
  if (t == 0){ bstart[NBMAX] = total; row_start[n] = total; }
}

// wev scaled by log2e; avecs = scaled attention vecs:
// [as1s 0..31 | ad1s 32..63 | as2s 64..95 | ad2s 96..127 | as3s 128..131 | ad3s 132..135]
__global__ void prep_kernel(const float* __restrict__ We, const float* __restrict__ ae,
                            const float* __restrict__ as1, const float* __restrict__ ad1,
                            const float* __restrict__ as2, const float* __restrict__ ad2,
                            const float* __restrict__ as3, const float* __restrict__ ad3,
                            float* __restrict__ wev, float* __restrict__ avecs){
  const float L2E = 1.4426950408889634f;
  int i = threadIdx.x;
  if (i < 32){
    int d = i >> 2, h = i & 3;
    float acc = 0.f;
    #pragma unroll
    for (int c = 0; c < 8; ++c) acc = fmaf(We[d * 32 + h * 8 + c], ae[h * 8 + c], acc);
    wev[d * 4 + h] = acc * L2E;
    avecs[i]      = as1[i] * L2E;
    avecs[32 + i] = ad1[i] * L2E;
    avecs[64 + i] = as2[i] * L2E;
    avecs[96 + i] = ad2[i] * L2E;
  }
  if (i < 4){
    avecs[128 + i] = as3[i] * L2E;
    avecs[132 + i] = ad3[i] * L2E;
  }
}

// multisplit v2: sort the whole chunk by bucket in LDS, then copy out densely.
__global__ __launch_bounds__(MS_THREADS)
void multisplit_kernel(const int* __restrict__ ei, int E, int CH,
                       const float* __restrict__ eattr, const float* __restrict__ wev,
                       const int* __restrict__ bstart, const int* __restrict__ prefix2d,
                       int4* __restrict__ staged){
  __shared__ int4 s_rec[CH_MAX];        // 50.2 KB
  __shared__ int s_fill[NBMAX];
  __shared__ int s_lbase[NBMAX];
  __shared__ int s_shift[NBMAX];
  __shared__ float s_wev[32];
  __shared__ int s_wsum[16];
  int t = threadIdx.x, chunk = blockIdx.x;
  if (t < 32) s_wev[t] = wev[t];
  s_fill[t] = 0;
  __syncthreads();
  int lo = chunk * CH, hi = min(lo + CH, E);
  int cnt = hi - lo;
  for (int e = lo + t; e < hi; e += MS_THREADS)
    atomicAdd(&s_fill[ei[E + e] >> W_SHIFT], 1);
  __syncthreads();
  int v = s_fill[t];
  int excl = block_exscan_1024(v, s_wsum, t);
  s_lbase[t] = excl;
  s_shift[t] = bstart[t] + prefix2d[(size_t)chunk * NBMAX + t] - excl;
  s_fill[t] = 0;
  __syncthreads();
  for (int e = lo + t; e < hi; e += MS_THREADS){
    int d = ei[E + e];
    int b = d >> W_SHIFT;
    const float4* ea = (const float4*)(eattr + (size_t)e * 8);
    float4 v0 = ea[0], v1 = ea[1];
    float av[8] = {v0.x, v0.y, v0.z, v0.w, v1.x, v1.y, v1.z, v1.w};
    float e0 = 0, e1 = 0, e2 = 0, e3 = 0;
    #pragma unroll
    for (int k = 0; k < 8; ++k){
      e0 = fmaf(av[k], s_wev[k * 4 + 0], e0);
      e1 = fmaf(av[k], s_wev[k * 4 + 1], e1);
      e2 = fmaf(av[k], s_wev[k * 4 + 2], e2);
      e3 = fmaf(av[k], s_wev[k * 4 + 3], e3);
    }
    __half2 h01 = __floats2half2_rn(e0, e1);
    __half2 h23 = __floats2half2_rn(e2, e3);
    int pos = s_lbase[b] + atomicAdd(&s_fill[b], 1);
    s_rec[pos] = make_int4(ei[e], d,
                           __builtin_bit_cast(int, h01), __builtin_bit_cast(int, h23));
  }
  __syncthreads();
  for (int i = t; i < cnt; i += MS_THREADS){
    int4 r = s_rec[i];
    staged[s_shift[r.y >> W_SHIFT] + i] = r;
  }
}

// per-bucket: counts -> row_start; permute staged to final CSR (srcs 4B + escp 8B);
// then 8-lane-per-node esc row sums from the L2-hot escp window -> selfesc.
__global__ __launch_bounds__(MS_THREADS)
void bucket_scatter_kernel(const int* __restrict__ bstart, const int4* __restrict__ staged,
                           int n, int* __restrict__ row_start, int* __restrict__ srcs,
                           uint2* __restrict__ escp, float4* __restrict__ selfesc){
  __shared__ int s_cnt[BUCKET_N];
  __shared__ int s_cur[BUCKET_N];
  __shared__ int s_start[BUCKET_N];
  __shared__ int s_wsum[2];
  int b = blockIdx.x, t = threadIdx.x;
  int node0 = b << W_SHIFT;
  if (t < BUCKET_N) s_cnt[t] = 0;
  __syncthreads();
  int lo = bstart[b], hi = bstart[b + 1];
  for (int i = lo + t; i < hi; i += MS_THREADS)
    atomicAdd(&s_cnt[staged[i].y & (BUCKET_N - 1)], 1);
  __syncthreads();
  // 128-value exclusive scan: 2 waves, shfl + 1 cross-wave fix
  int lane = t & 63, w = t >> 6;
  if (w < 2){
    int v = s_cnt[t];
    int x = v;
    #pragma unroll
    for (int off = 1; off < 64; off <<= 1){
      int u = __shfl_up(x, off, 64);
      if (lane >= off) x += u;
    }
    if (lane == 63) s_wsum[w] = x;
    s_cur[t] = x - v;                     // wave-local exclusive
  }
  __syncthreads();
  if (t < BUCKET_N){
    int excl = s_cur[t] + (w ? s_wsum[0] : 0);
    int nd = node0 + t;
    if (nd <= n) row_start[nd] = lo + excl;
    s_start[t] = lo + excl;
    s_cur[t] = lo + excl;
  }
  __syncthreads();
  for (int i = lo + t; i < hi; i += MS_THREADS){
    int4 r = staged[i];
    int pos = atomicAdd(&s_cur[r.y & (BUCKET_N - 1)], 1);
    srcs[pos] = r.x;
    escp[pos] = make_uint2((unsigned)r.z, (unsigned)r.w);
  }
  __syncthreads();
  int nl = t >> 3, sub = t & 7;
  int nd2 = node0 + nl;
  if (nd2 >= n) return;
  int r0 = s_start[nl], r1 = s_start[nl] + s_cnt[nl];
  float e0 = 0, e1 = 0, e2 = 0, e3 = 0;
  for (int k = r0 + sub; k < r1; k += 8){
    uint2 u = escp[k];
    float2 f01 = __half22float2(__builtin_bit_cast(__half2, u.x));
    float2 f23 = __half22float2(__builtin_bit_cast(__half2, u.y));
    e0 += f01.x; e1 += f01.y; e2 += f23.x; e3 += f23.y;
  }
  #pragma unroll
  for (int off = 1; off < 8; off <<= 1){
    e0 += __shfl_xor(e0, off, 64); e1 += __shfl_xor(e1, off, 64);
    e2 += __shfl_xor(e2, off, 64); e3 += __shfl_xor(e3, off, 64);
  }
  if (sub == 0){
    float inv = 1.f / fmaxf((float)s_cnt[nl], 1.f);
    selfesc[nd2] = make_float4(e0 * inv, e1 * inv, e2 * inv, e3 * inv);
  }
}

// ---------------- register-tiled node transform (pure GEMM) ----------------
template<int K>
__global__ __launch_bounds__(256)
void gemm_tiled(const float* __restrict__ A, const float* __restrict__ W,
                float* __restrict__ out, int n){
  constexpr int KH = (K > 64) ? 64 : K;
  constexpr int K4 = KH / 4;
  __shared__ float s_AT[KH * 128];
  __shared__ float s_W[K * 32];
  int t = threadIdx.x;
  for (int i = t; i < K * 32; i += 256) s_W[i] = W[i];
  int n0 = blockIdx.x * 128;
  int nrows = min(128, n - n0);
  int rg = t >> 3, q = t & 7;
  float4 acc[4] = {{0,0,0,0},{0,0,0,0},{0,0,0,0},{0,0,0,0}};

  for (int k0 = 0; k0 < K; k0 += KH){
    __syncthreads();
    #pragma unroll
    for (int it = 0; it < 128 * K4 / 256; ++it){
      int idx = t + it * 256;
      int row = idx & 127, k4 = idx >> 7;
      if (row < nrows){
        float4 v = *(const float4*)(A + (size_t)(n0 + row) * K + k0 + 4 * k4);
        s_AT[(4 * k4 + 0) * 128 + row] = v.x;
        s_AT[(4 * k4 + 1) * 128 + row] = v.y;
        s_AT[(4 * k4 + 2) * 128 + row] = v.z;
        s_AT[(4 * k4 + 3) * 128 + row] = v.w;
      }
    }
    __syncthreads();
    #pragma unroll 4
    for (int k = 0; k < KH; ++k){
      float4 a4 = *(const float4*)(s_AT + k * 128 + 4 * rg);
      float4 w4 = *(const float4*)(s_W + (k0 + k) * 32 + 4 * q);
      acc[0].x = fmaf(a4.x, w4.x, acc[0].x); acc[0].y = fmaf(a4.x, w4.y, acc[0].y);
      acc[0].z = fmaf(a4.x, w4.z, acc[0].z); acc[0].w = fmaf(a4.x, w4.w, acc[0].w);
      acc[1].x = fmaf(a4.y, w4.x, acc[1].x); acc[1].y = fmaf(a4.y, w4.y, acc[1].y);
      acc[1].z = fmaf(a4.y, w4.z, acc[1].z); acc[1].w = fmaf(a4.y, w4.w, acc[1].w);
      acc[2].x = fmaf(a4.z, w4.x, acc[2].x); acc[2].y = fmaf(a4.z, w4.y, acc[2].y);
      acc[2].z = fmaf(a4.z, w4.z, acc[2].z); acc[2].w = fmaf(a4.z, w4.w, acc[2].w);
      acc[3].x = fmaf(a4.w, w4.x, acc[3].x); acc[3].y = fmaf(a4.w, w4.y, acc[3].y);
      acc[3].z = fmaf(a4.w, w4.z, acc[3].z); acc[3].w = fmaf(a4.w, w4.w, acc[3].w);
    }
  }
  #pragma unroll
  for (int i = 0; i < 4; ++i){
    int row = n0 + 4 * rg + i;
    if ((4 * rg + i) < nrows) ((float4*)out)[(size_t)row * 8 + q] = acc[i];
  }
}

// ---------------- one-phase CSR gather: 4 lanes/edge, srcs/escp prefetch ----------------
// lane = (sg 0..15, h 0..3): 16 edges in flight; head h's full 8 elements in-lane.
template<int MODE, bool EDGE>
__global__ void gather_kernel(const int* __restrict__ row_start, const int* __restrict__ srcs,
                              const uint2* __restrict__ escp, const float4* __restrict__ selfesc,
                              const float* __restrict__ xh, const float* __restrict__ avq,
                              const float* __restrict__ bias, float* __restrict__ out, int n,
                              const float* __restrict__ W3p, float* __restrict__ xh3){
  int wv = threadIdx.x >> 6, lane = threadIdx.x & 63;
  int node = blockIdx.x * 4 + wv;

  if constexpr (MODE == 2){
    if (node >= n) return;
    int rs = row_start[node], deg = row_start[node + 1] - rs;
    float4 a3s = *(const float4*)avq;
    float4 a3d = *(const float4*)(avq + 4);
    float4 xvn = ((const float4*)xh)[node];
    float4 sdn = {xvn.x * a3d.x, xvn.y * a3d.y, xvn.z * a3d.z, xvn.w * a3d.w};
    float4 acc = {0,0,0,0}, dsum = {0,0,0,0};
    for (int k = lane; k < deg; k += 64){
      int s = srcs[rs + k];
      float4 xv = ((const float4*)xh)[s];
      float4 w;
      w.x = fexp2(lrelu(fmaf(xv.x, a3s.x, sdn.x)));
      w.y = fexp2(lrelu(fmaf(xv.y, a3s.y, sdn.y)));
      w.z = fexp2(lrelu(fmaf(xv.z, a3s.z, sdn.z)));
      w.w = fexp2(lrelu(fmaf(xv.w, a3s.w, sdn.w)));
      dsum.x += w.x; dsum.y += w.y; dsum.z += w.z; dsum.w += w.w;
      acc.x = fmaf(w.x, xv.x, acc.x); acc.y = fmaf(w.y, xv.y, acc.y);
      acc.z = fmaf(w.z, xv.z, acc.z); acc.w = fmaf(w.w, xv.w, acc.w);
    }
    #pragma unroll
    for (int off = 1; off < 64; off <<= 1){
      acc.x += __shfl_xor(acc.x, off, 64); acc.y += __shfl_xor(acc.y, off, 64);
      acc.z += __shfl_xor(acc.z, off, 64); acc.w += __shfl_xor(acc.w, off, 64);
      dsum.x += __shfl_xor(dsum.x, off, 64); dsum.y += __shfl_xor(dsum.y, off, 64);
      dsum.z += __shfl_xor(dsum.z, off, 64); dsum.w += __shfl_xor(dsum.w, off, 64);
    }
    if (lane == 0){
      float4 wsf;
      wsf.x = fexp2(lrelu(fmaf(xvn.x, a3s.x, sdn.x)));
      wsf.y = fexp2(lrelu(fmaf(xvn.y, a3s.y, sdn.y)));
      wsf.z = fexp2(lrelu(fmaf(xvn.z, a3s.z, sdn.z)));
      wsf.w = fexp2(lrelu(fmaf(xvn.w, a3s.w, sdn.w)));
      float v = (acc.x + wsf.x * xvn.x) / (dsum.x + wsf.x + 1e-16f)
              + (acc.y + wsf.y * xvn.y) / (dsum.y + wsf.y + 1e-16f)
              + (acc.z + wsf.z * xvn.z) / (dsum.z + wsf.z + 1e-16f)
              + (acc.w + wsf.w * xvn.w) / (dsum.w + wsf.w + 1e-16f);
      out[node] = 0.25f * v + bias[0];
    }
    return;
  } else {
  __shared__ float s_w3[32];
  if constexpr (MODE == 1){
    if (threadIdx.x < 32) s_w3[threadIdx.x] = W3p[threadIdx.x];
    __syncthreads();
  }
  if (node >= n) return;
  int rs = row_start[node], deg = row_start[node + 1] - rs;
  int h = lane & 3, sg = lane >> 2;          // head, edge slot (16 edges/iter)
  const float4* xh4 = (const float4*)xh;
  float4 as0 = ((const float4*)avq)[2 * h];
  float4 as1v = ((const float4*)avq)[2 * h + 1];
  float4 ad0 = ((const float4*)(avq + 32))[2 * h];
  float4 ad1v = ((const float4*)(avq + 32))[2 * h + 1];
  float4 xn0 = xh4[(size_t)node * 8 + 2 * h];
  float4 xn1 = xh4[(size_t)node * 8 + 2 * h + 1];
  float sdh = dot8(xn0, xn1, ad0, ad1v);
  float4 acc0 = {0,0,0,0}, acc1 = {0,0,0,0};
  float dacc = 0.f;
  const int* sp = srcs + rs;

  // prefetch pipeline: srcs (and escp) for iteration i loaded during i-1
  int k = sg;
  int s_cur = (k < deg) ? sp[k] : -1;
  uint2 u_cur = (EDGE && k < deg) ? escp[rs + k] : make_uint2(0u, 0u);
  for (int base = 0; base < deg; base += 16){
    int k2 = base + 16 + sg;
    int s_nxt = (k2 < deg) ? sp[k2] : -1;
    uint2 u_nxt = (EDGE && k2 < deg) ? escp[rs + k2] : make_uint2(0u, 0u);
    if (s_cur >= 0){
      float4 xv0 = xh4[(size_t)s_cur * 8 + 2 * h];
      float4 xv1 = xh4[(size_t)s_cur * 8 + 2 * h + 1];
      float a = dot8(xv0, xv1, as0, as1v) + sdh;
      if constexpr (EDGE){
        float2 f01 = __half22float2(__builtin_bit_cast(__half2, u_cur.x));
        float2 f23 = __half22float2(__builtin_bit_cast(__half2, u_cur.y));
        a += (h == 0) ? f01.x : (h == 1) ? f01.y : (h == 2) ? f23.x : f23.y;
      }
      float w = fexp2(lrelu(a));
      dacc += w;
      acc0.x = fmaf(w, xv0.x, acc0.x); acc0.y = fmaf(w, xv0.y, acc0.y);
      acc0.z = fmaf(w, xv0.z, acc0.z); acc0.w = fmaf(w, xv0.w, acc0.w);
      acc1.x = fmaf(w, xv1.x, acc1.x); acc1.y = fmaf(w, xv1.y, acc1.y);
      acc1.z = fmaf(w, xv1.z, acc1.z); acc1.w = fmaf(w, xv1.w, acc1.w);
    }
    s_cur = s_nxt;
    u_cur = u_nxt;
  }

  #pragma unroll
  for (int off = 4; off < 64; off <<= 1){
    acc0.x += __shfl_xor(acc0.x, off, 64); acc0.y += __shfl_xor(acc0.y, off, 64);
    acc0.z += __shfl_xor(acc0.z, off, 64); acc0.w += __shfl_xor(acc0.w, off, 64);
    acc1.x += __shfl_xor(acc1.x, off, 64); acc1.y += __shfl_xor(acc1.y, off, 64);
    acc1.z += __shfl_xor(acc1.z, off, 64); acc1.w += __shfl_xor(acc1.w, off, 64);
    dacc   += __shfl_xor(dacc,   off, 64);
  }
  float a_self = dot8(xn0, xn1, as0, as1v) + sdh;
  if constexpr (EDGE) a_self += sel4(selfesc[node], h);
  float wsel = fexp2(lrelu(a_self));
  acc0.x = fmaf(wsel, xn0.x, acc0.x); acc0.y = fmaf(wsel, xn0.y, acc0.y);
  acc0.z = fmaf(wsel, xn0.z, acc0.z); acc0.w = fmaf(wsel, xn0.w, acc0.w);
  acc1.x = fmaf(wsel, xn1.x, acc1.x); acc1.y = fmaf(wsel, xn1.y, acc1.y);
  acc1.z = fmaf(wsel, xn1.z, acc1.z); acc1.w = fmaf(wsel, xn1.w, acc1.w);
  dacc += wsel;
  float rin = 1.f / (dacc + 1e-16f);
  float4 v0 = {acc0.x * rin, acc0.y * rin, acc0.z * rin, acc0.w * rin};
  float4 v1 = {acc1.x * rin, acc1.y * rin, acc1.z * rin, acc1.w * rin};

  if constexpr (MODE == 0){
    if (sg == 0){
      float4 ba = ((const float4*)bias)[2 * h];
      float4 bb = ((const float4*)bias)[2 * h + 1];
      v0.x = elu1(v0.x + ba.x); v0.y = elu1(v0.y + ba.y);
      v0.z = elu1(v0.z + ba.z); v0.w = elu1(v0.w + ba.w);
      v1.x = elu1(v1.x + bb.x); v1.y = elu1(v1.y + bb.y);
      v1.z = elu1(v1.z + bb.z); v1.w = elu1(v1.w + bb.w);
      ((float4*)out)[(size_t)node * 8 + 2 * h] = v0;
      ((float4*)out)[(size_t)node * 8 + 2 * h + 1] = v1;
    }
  } else {
    #pragma unroll
    for (int off = 1; off < 4; off <<= 1){
      v0.x += __shfl_xor(v0.x, off, 64); v0.y += __shfl_xor(v0.y, off, 64);
      v0.z += __shfl_xor(v0.z, off, 64); v0.w += __shfl_xor(v0.w, off, 64);
      v1.x += __shfl_xor(v1.x, off, 64); v1.y += __shfl_xor(v1.y, off, 64);
      v1.z += __shfl_xor(v1.z, off, 64); v1.w += __shfl_xor(v1.w, off, 64);
    }
    float4 ba = ((const float4*)bias)[0];
    float4 bb = ((const float4*)bias)[1];
    float h2v[8];
    h2v[0] = elu1(v0.x * 0.25f + ba.x); h2v[1] = elu1(v0.y * 0.25f + ba.y);
    h2v[2] = elu1(v0.z * 0.25f + ba.z); h2v[3] = elu1(v0.w * 0.25f + ba.w);
    h2v[4] = elu1(v1.x * 0.25f + bb.x); h2v[5] = elu1(v1.y * 0.25f + bb.y);
    h2v[6] = elu1(v1.z * 0.25f + bb.z); h2v[7] = elu1(v1.w * 0.25f + bb.w);
    if (sg == 0){
      float a = 0.f;
      #pragma unroll
      for (int kk = 0; kk < 8; ++kk) a = fmaf(h2v[kk], s_w3[kk * 4 + h], a);
      xh3[(size_t)node * 4 + h] = a;
    }
  }
  }
}

// ---------------- launcher ----------------

extern "C" void kernel_launch(void* const* d_in, const int* in_sizes, int n_in,
                              void* d_out, int out_size, void* d_ws, size_t ws_size,
                              hipStream_t stream){
  const float* x     = (const float*)d_in[0];
  const float* eattr = (const float*)d_in[1];
  const int*   ei    = (const int*)d_in[2];
  const float* W1  = (const float*)d_in[3];
  const float* as1 = (const float*)d_in[4];
  const float* ad1 = (const float*)d_in[5];
  const float* We1 = (const float*)d_in[6];
  const float* ae1 = (const float*)d_in[7];
  const float* b1  = (const float*)d_in[8];
  const float* W2  = (const float*)d_in[9];
  const float* as2 = (const float*)d_in[10];
  const float* ad2 = (const float*)d_in[11];
  const float* b2  = (const float*)d_in[12];
  const float* W3  = (const float*)d_in[13];
  const float* as3 = (const float*)d_in[14];
  const float* ad3 = (const float*)d_in[15];
  const float* b3  = (const float*)d_in[16];

  const int N = in_sizes[0] / 128;
  const int E = in_sizes[2] / 2;
  const int nb_buckets = (N + BUCKET_N - 1) >> W_SHIFT;   // 782 for N=100000
  const int CH = cdiv(E, NCHUNKS);                        // 3125 (<= CH_MAX)

  char* b0 = (char*)d_ws;
  int4* staged = (int4*)b0;                 // E*16; aliased by xh/h1 after CSR build
  float* fp = (float*)b0;
  float* xh = fp; fp += (size_t)N * 32;
  float* h1 = fp; fp += (size_t)N * 32;
  int*  srcs = (int*)(b0 + (size_t)E * 16);
  uint2* escp = (uint2*)(b0 + (size_t)E * 20);
  int* hist2d = (int*)(b0 + (size_t)E * 28);
  float4* selfesc = (float4*)(hist2d + (size_t)NCHUNKS * NBMAX);
  float* xh3 = (float*)(selfesc + N);
  int* ip = (int*)(xh3 + (size_t)N * 4);
  int* bcnt      = ip; ip += NBMAX;
  int* bstart    = ip; ip += NBMAX + 1;
  int* row_start = ip; ip += N + 1;
  float* wev   = (float*)ip;
  float* avecs = wev + 32;

  const int B = 256;

  // ---- CSR build: plan (no global atomics) -> LDS-sorted multisplit -> bucket scatter ----
  prep_kernel<<<1, 64, 0, stream>>>(We1, ae1, as1, ad1, as2, ad2, as3, ad3, wev, avecs);
  hist_chunks_kernel<<<NCHUNKS, MS_THREADS, 0, stream>>>(ei, E, CH, hist2d);
  col_scan_kernel<<<nb_buckets, NCHUNKS, 0, stream>>>(hist2d, bcnt);
  scan_buckets_kernel<<<1, 1024, 0, stream>>>(bcnt, nb_buckets, E, bstart, row_start, N);
  multisplit_kernel<<<NCHUNKS, MS_THREADS, 0, stream>>>(ei, E, CH, eattr, wev, bstart, hist2d, staged);
  bucket_scatter_kernel<<<nb_buckets, MS_THREADS, 0, stream>>>(bstart, staged, N, row_start, srcs, escp, selfesc);

  // ---- layer 1: 128 -> 4x8, concat, edge scores ----
  gemm_tiled<128><<<cdiv(N, 128), B, 0, stream>>>(x, W1, xh, N);
  gather_kernel<0,true><<<cdiv(N, 4), B, 0, stream>>>(row_start, srcs, escp, selfesc, xh, avecs,
                                                      b1, h1, N, nullptr, nullptr);

  // ---- layer 2: 32 -> 4x8, mean heads; fused layer-3 transform ----
  gemm_tiled<32><<<cdiv(N, 128), B, 0, stream>>>(h1, W2, xh, N);
  gather_kernel<1,false><<<cdiv(N, 4), B, 0, stream>>>(row_start, srcs, escp, selfesc, xh, avecs + 64,
                                                       b2, nullptr, N, W3, xh3);

  // ---- layer 3: 8 -> 4x1, mean heads (xh3 table, scores componentwise) ----
  gather_kernel<2,false><<<cdiv(N, 4), B, 0, stream>>>(row_start, srcs, escp, selfesc, xh3, avecs + 128,
                                                       b3, (float*)d_out, N, nullptr, nullptr);
}